// Round 14
// baseline (715.288 us; speedup 1.0000x reference)
//
#include <hip/hip_runtime.h>
#include <cstdint>
#include <cstddef>

typedef unsigned short u16;
typedef __attribute__((ext_vector_type(4))) float f32x4;
typedef __attribute__((ext_vector_type(4))) float f4;
typedef __attribute__((ext_vector_type(8))) short short8x;
typedef __attribute__((ext_vector_type(4))) u16 u16x4;
typedef __attribute__((ext_vector_type(8))) u16 u16x8;

#define DEV static __device__ __forceinline__
#define VMC4() asm volatile("s_waitcnt vmcnt(4)" ::: "memory")
#define VMC0() asm volatile("s_waitcnt vmcnt(0)" ::: "memory")
#define BARR() asm volatile("s_barrier" ::: "memory")

DEV void gl_lds16(const void* g, void* l) {
  __builtin_amdgcn_global_load_lds(
      (const __attribute__((address_space(1))) unsigned int*)g,
      (__attribute__((address_space(3))) unsigned int*)l, 16, 0, 0);
}

DEV u16 f2bf(float f) {
  unsigned u = __float_as_uint(f);
  u += 0x7fffu + ((u >> 16) & 1u);
  return (u16)(u >> 16);
}

// ---------------- cast / pack kernels ----------------

__global__ __launch_bounds__(256) void cast_bf16_2(const float* __restrict__ X0, const float* __restrict__ X1,
                                                   u16* __restrict__ Y0, u16* __restrict__ Y1) {
  const float* X = blockIdx.y ? X1 : X0;
  u16* Y = blockIdx.y ? Y1 : Y0;
  size_t i = ((size_t)blockIdx.x * 256 + threadIdx.x) * 4;
  f4 v = *(const f4*)(X + i);
  u16x4 y;
#pragma unroll
  for (int j = 0; j < 4; ++j) y[j] = f2bf(v[j]);
  *(u16x4*)(Y + i) = y;
}

// 6x wq [H,D,DH] f32 -> Wt [H*DH, D] bf16 (B^T form), dsts contiguous at Wbase + z*1M elems
__global__ __launch_bounds__(256) void cast_wqkv6(const float* __restrict__ W0, const float* __restrict__ W1,
                                                  const float* __restrict__ W2, const float* __restrict__ W3,
                                                  const float* __restrict__ W4, const float* __restrict__ W5,
                                                  u16* __restrict__ Wbase) {
  __shared__ float tile[64][65];
  const int t = threadIdx.x;
  const int h = blockIdx.y;
  const int z = blockIdx.z;
  const int d0 = blockIdx.x * 64;
  const float* W = (z == 0) ? W0 : (z == 1) ? W1 : (z == 2) ? W2 : (z == 3) ? W3 : (z == 4) ? W4 : W5;
  u16* Wt = Wbase + (size_t)z * (1024 * 1024);
  const float* Wb = W + (size_t)h * (1024 * 64);
  const int di = t >> 2;
  const int j0 = (t & 3) * 16;
#pragma unroll
  for (int c = 0; c < 4; ++c) {
    f4 v = *(const f4*)(Wb + (size_t)(d0 + di) * 64 + j0 + c * 4);
#pragma unroll
    for (int j = 0; j < 4; ++j) tile[di][j0 + c * 4 + j] = v[j];
  }
  __syncthreads();
  const int k = t >> 2;
  const int dd0 = (t & 3) * 16;
  u16x8 o0, o1;
#pragma unroll
  for (int u = 0; u < 8; ++u) o0[u] = f2bf(tile[dd0 + u][k]);
#pragma unroll
  for (int u = 0; u < 8; ++u) o1[u] = f2bf(tile[dd0 + 8 + u][k]);
  u16* dst = Wt + (size_t)(h * 64 + k) * 1024 + d0 + dd0;
  *(u16x8*)(dst) = o0;
  *(u16x8*)(dst + 8) = o1;
}

// V columns of src [B,S,vstride] bf16 -> Vt [B*H, DH, S] bf16
__global__ __launch_bounds__(256) void transpose_v(const u16* __restrict__ V, u16* __restrict__ Vt,
                                                   int vstride, int voff) {
  __shared__ u16 tile[32][72];
  const int t = threadIdx.x;
  const int bh = blockIdx.y;
  const int s0 = blockIdx.x * 32;
  const u16* Vb = V + (size_t)(bh >> 4) * (1024 * (size_t)vstride) + voff + (bh & 15) * 64;
  const int si = t >> 3, d0 = (t & 7) * 8;
  u16x8 val = *(const u16x8*)(Vb + (size_t)(s0 + si) * vstride + d0);
#pragma unroll
  for (int u = 0; u < 8; ++u) tile[si][d0 + u] = val[u];
  __syncthreads();
  const int d = t >> 2, sj0 = (t & 3) * 8;
  u16x8 o;
#pragma unroll
  for (int u = 0; u < 8; ++u) o[u] = tile[sj0 + u][d];
  *(u16x8*)(Vt + (size_t)bh * (64 * 1024) + (size_t)d * 1024 + s0 + sj0) = o;
}

// -------- GEMM 128x128, BK=32, 3-buffer rotate, stage-after-compute, vmcnt(4) --------
// C[M,N](ldc) = A[M,:]*B^T over K-chunk [z*Kit, (z+1)*Kit), rows stride Krow.
// Step s: vmcnt(4) [drains buf s] -> barrier -> compute(buf s%3) -> stage(buf (s+2)%3).
// Race-free: staged buf == buf[(s-1)%3], last read in compute(s-1); stage is issued only
// after barrier(s), which every wave passes only after finishing compute(s-1).
// EPI: 0=bf16, 1=f32, 2=bias+GELU->bf16, 4=scale(1/8)->bf16, 5=QKV scale cols<1024
template <int EPI>
__global__ __launch_bounds__(256, 3) void gemm_bt(const u16* __restrict__ A, const u16* __restrict__ Bt,
                                                  void* __restrict__ C, const float* __restrict__ bias,
                                                  int Krow, int Kit, int ldc, long long zC) {
  __shared__ u16 As0[128 * 32], Bs0[128 * 32];
  __shared__ u16 As1[128 * 32], Bs1[128 * 32];
  __shared__ u16 As2[128 * 32], Bs2[128 * 32];  // 48KB total -> 3 blocks/CU
  const int t = threadIdx.x;
  const int wave = t >> 6, lane = t & 63;
  const int lr = lane & 15, lkg = lane >> 4;
  const int swz = (lr >> 1) & 3;
  const int wr = (wave >> 1) * 64, wc = (wave & 1) * 64;

  const int gx = gridDim.x;
  const int nwg = gx * gridDim.y;
  const int flat = blockIdx.y * gx + blockIdx.x;
  const int wg = (flat & 7) * (nwg >> 3) + (flat >> 3);
  const int m0 = (wg / gx) * 128, n0 = (wg % gx) * 128;

  const int schunk = ((t & 3) ^ ((t >> 3) & 3)) << 4;
  const size_t rowb = (size_t)Krow * 2;
  const size_t rowskip = (size_t)64 * rowb;
  const size_t zoff = (size_t)blockIdx.z * (size_t)Kit * 2;
  const char* gA0 = (const char*)A + (size_t)(m0 + (t >> 2)) * rowb + zoff + schunk;
  const char* gA1 = gA0 + rowskip;
  const char* gB0 = (const char*)Bt + (size_t)(n0 + (t >> 2)) * rowb + zoff + schunk;
  const char* gB1 = gB0 + rowskip;

  // per-buffer stage destinations (wave-uniform) and read bases (lane-constant)
  const int aoff = (wr + lr) * 64 + ((lkg ^ swz) << 4);
  const int boff = (wc + lr) * 64 + ((lkg ^ swz) << 4);
  char* dA_c = (char*)As0 + wave * 1024;  char* dB_c = (char*)Bs0 + wave * 1024;
  char* dA_n = (char*)As1 + wave * 1024;  char* dB_n = (char*)Bs1 + wave * 1024;
  char* dA_t = (char*)As2 + wave * 1024;  char* dB_t = (char*)Bs2 + wave * 1024;
  const char* rA_c = (const char*)As0 + aoff;  const char* rB_c = (const char*)Bs0 + boff;
  const char* rA_n = (const char*)As1 + aoff;  const char* rB_n = (const char*)Bs1 + boff;
  const char* rA_t = (const char*)As2 + aoff;  const char* rB_t = (const char*)Bs2 + boff;

  const f32x4 fzero = {0.f, 0.f, 0.f, 0.f};
  f32x4 acc[4][4];
#pragma unroll
  for (int m = 0; m < 4; ++m)
#pragma unroll
    for (int n = 0; n < 4; ++n) acc[m][n] = fzero;

  auto stageTo = [&](char* da, char* db) {
    gl_lds16(gA0, da); gl_lds16(gA1, da + 4096);
    gl_lds16(gB0, db); gl_lds16(gB1, db + 4096);
    gA0 += 64; gA1 += 64; gB0 += 64; gB1 += 64;
  };
  auto compute = [&](const char* rA, const char* rB) {
    short8x aF[4], bF[4];
#pragma unroll
    for (int m = 0; m < 4; ++m) aF[m] = *(const short8x*)(rA + m * 1024);
#pragma unroll
    for (int n = 0; n < 4; ++n) bF[n] = *(const short8x*)(rB + n * 1024);
#pragma unroll
    for (int m = 0; m < 4; ++m)
#pragma unroll
      for (int n = 0; n < 4; ++n)
        acc[m][n] = __builtin_amdgcn_mfma_f32_16x16x32_bf16(aF[m], bF[n], acc[m][n], 0, 0, 0);
  };

  const int nk = Kit >> 5;  // BK=32 steps (nk >= 3)
  // prologue: stage kt=0 -> buf0, kt=1 -> buf1  [outstanding 8]
  stageTo(dA_c, dB_c);
  stageTo(dA_n, dB_n);

  for (int s = 0; s < nk; ++s) {
    if (s + 1 < nk) { VMC4(); } else { VMC0(); }
    BARR();
    compute(rA_c, rB_c);
    if (s + 2 < nk) stageTo(dA_t, dB_t);
    // rotate: cur <- next <- third <- cur
    char* ta = dA_c; dA_c = dA_n; dA_n = dA_t; dA_t = ta;
    char* tb = dB_c; dB_c = dB_n; dB_n = dB_t; dB_t = tb;
    const char* ra = rA_c; rA_c = rA_n; rA_n = rA_t; rA_t = ra;
    const char* rb = rB_c; rB_c = rB_n; rB_n = rB_t; rB_t = rb;
  }

  // ---- epilogue ----
#pragma unroll
  for (int m = 0; m < 4; ++m) {
#pragma unroll
    for (int rr = 0; rr < 4; ++rr) {
      const int gm = m0 + wr + m * 16 + lkg * 4 + rr;
#pragma unroll
      for (int n = 0; n < 4; ++n) {
        const int gn = n0 + wc + n * 16 + lr;
        float v = acc[m][n][rr];
        if (EPI == 2) v += bias[gn];
        if (EPI == 2) v = 0.5f * v * (1.0f + erff(v * 0.70710678118654752f));
        if (EPI == 4) v *= 0.125f;
        if (EPI == 5 && gn < 1024) v *= 0.125f;
        if (EPI == 1)
          ((float*)C)[(size_t)blockIdx.z * zC + (size_t)gm * ldc + gn] = v;
        else
          ((u16*)C)[(size_t)gm * ldc + gn] = f2bf(v);
      }
    }
  }
}

// ---- merged Q2 (scale 1/8 -> QKV ldc 3072) + KV2 (plain -> KV2buf ldc 2048), R12-verified ----
__global__ __launch_bounds__(256, 3) void gemm_q2kv2(const u16* __restrict__ A1, const u16* __restrict__ B1,
                                                     u16* __restrict__ C1, const u16* __restrict__ A2,
                                                     const u16* __restrict__ B2, u16* __restrict__ C2) {
  __shared__ u16 As0[128 * 32], Bs0[128 * 32];
  __shared__ u16 As1[128 * 32], Bs1[128 * 32];
  const int t = threadIdx.x;
  const int wave = t >> 6, lane = t & 63;
  const int lr = lane & 15, lkg = lane >> 4;
  const int swz = (lr >> 1) & 3;
  const int wr = (wave >> 1) * 64, wc = (wave & 1) * 64;

  const int nwg = 24 * 64;
  const int flat = blockIdx.y * 24 + blockIdx.x;
  const int wg = (flat & 7) * (nwg >> 3) + (flat >> 3);

  const int sub = (wg >= 512);
  const int wl = sub ? (wg - 512) : wg;
  const int gxl = sub ? 16 : 8;
  const int m0 = (wl / gxl) * 128, n0 = (wl % gxl) * 128;
  const u16* A = sub ? A2 : A1;
  const u16* Bt = sub ? B2 : B1;
  u16* C = sub ? C2 : C1;
  const int ldc = sub ? 2048 : 3072;
  const float scale = sub ? 1.0f : 0.125f;

  const int schunk = ((t & 3) ^ ((t >> 3) & 3)) << 4;
  const size_t rowb = 2048;
  const size_t rowskip = (size_t)64 * rowb;
  const char* gA0 = (const char*)A + (size_t)(m0 + (t >> 2)) * rowb + schunk;
  const char* gA1 = gA0 + rowskip;
  const char* gB0 = (const char*)Bt + (size_t)(n0 + (t >> 2)) * rowb + schunk;
  const char* gB1 = gB0 + rowskip;

  char* dA0 = (char*)As0 + wave * 1024;
  char* dB0 = (char*)Bs0 + wave * 1024;
  char* dA1 = (char*)As1 + wave * 1024;
  char* dB1 = (char*)Bs1 + wave * 1024;

  const int aoff = (wr + lr) * 64 + ((lkg ^ swz) << 4);
  const int boff = (wc + lr) * 64 + ((lkg ^ swz) << 4);
  const char* rA0 = (const char*)As0 + aoff;
  const char* rB0 = (const char*)Bs0 + boff;
  const char* rA1 = (const char*)As1 + aoff;
  const char* rB1 = (const char*)Bs1 + boff;

  const f32x4 fzero = {0.f, 0.f, 0.f, 0.f};
  f32x4 acc[4][4];
#pragma unroll
  for (int m = 0; m < 4; ++m)
#pragma unroll
    for (int n = 0; n < 4; ++n) acc[m][n] = fzero;

  auto compute = [&](const char* rA, const char* rB) {
    short8x aF[4], bF[4];
#pragma unroll
    for (int m = 0; m < 4; ++m) aF[m] = *(const short8x*)(rA + m * 1024);
#pragma unroll
    for (int n = 0; n < 4; ++n) bF[n] = *(const short8x*)(rB + n * 1024);
#pragma unroll
    for (int m = 0; m < 4; ++m)
#pragma unroll
      for (int n = 0; n < 4; ++n)
        acc[m][n] = __builtin_amdgcn_mfma_f32_16x16x32_bf16(aF[m], bF[n], acc[m][n], 0, 0, 0);
  };

  gl_lds16(gA0, dA0); gl_lds16(gA1, dA0 + 4096);
  gl_lds16(gB0, dB0); gl_lds16(gB1, dB0 + 4096);
  gA0 += 64; gA1 += 64; gB0 += 64; gB1 += 64;
  __syncthreads();

  for (int p = 0; p < 16; ++p) {
    gl_lds16(gA0, dA1); gl_lds16(gA1, dA1 + 4096);
    gl_lds16(gB0, dB1); gl_lds16(gB1, dB1 + 4096);
    gA0 += 64; gA1 += 64; gB0 += 64; gB1 += 64;
    compute(rA0, rB0);
    __syncthreads();
    if (p + 1 < 16) {
      gl_lds16(gA0, dA0); gl_lds16(gA1, dA0 + 4096);
      gl_lds16(gB0, dB0); gl_lds16(gB1, dB0 + 4096);
    }
    gA0 += 64; gA1 += 64; gB0 += 64; gB1 += 64;
    compute(rA1, rB1);
    __syncthreads();
  }

#pragma unroll
  for (int m = 0; m < 4; ++m) {
#pragma unroll
    for (int rr = 0; rr < 4; ++rr) {
      const int gm = m0 + wr + m * 16 + lkg * 4 + rr;
#pragma unroll
      for (int n = 0; n < 4; ++n) {
        const int gn = n0 + wc + n * 16 + lr;
        C[(size_t)gm * ldc + gn] = f2bf(acc[m][n][rr] * scale);
      }
    }
  }
}

// ---------------- flash attention (verified; separate Q/K strides, causal longest-first) ----------------
template <int CAUSAL>
__global__ __launch_bounds__(256, 2) void flash_attn(const u16* __restrict__ Q, const u16* __restrict__ Kk,
                                                     const u16* __restrict__ Vt, u16* __restrict__ O,
                                                     int qst, int kst) {
  __shared__ u16 Ks[2][64 * 64];
  __shared__ u16 Vs[2][64 * 64];
  __shared__ u16 Ps[4][32 * 72];
  const int t = threadIdx.x;
  const int wave = t >> 6, lane = t & 63;
  const int lr = lane & 15, lkg = lane >> 4, lk = lkg * 8;
  const int sw = lr & 7;
  const int bh = blockIdx.y;
  const u16* Qb = Q + (size_t)(bh >> 4) * (1024 * (size_t)qst) + (bh & 15) * 64;
  const u16* Kb = Kk + (size_t)(bh >> 4) * (1024 * (size_t)kst) + (bh & 15) * 64;
  const u16* Vtb = Vt + (size_t)bh * (64 * 1024);
  u16* Ob = O + (size_t)(bh >> 4) * (1024 * 1024) + (bh & 15) * 64;
  const int qt = (gridDim.x - 1 - blockIdx.x) * 128;
  const int qw = qt + wave * 32;

  const f32x4 fzero = {0.f, 0.f, 0.f, 0.f};
  short8x qf[2][2];
#pragma unroll
  for (int rb = 0; rb < 2; ++rb)
#pragma unroll
    for (int kk = 0; kk < 2; ++kk)
      qf[rb][kk] = *(const short8x*)(Qb + (size_t)(qw + rb * 16 + lr) * qst + kk * 32 + lk);

  float m_[2][4], l_[2][4];
  f32x4 o_[2][4];
#pragma unroll
  for (int rb = 0; rb < 2; ++rb) {
#pragma unroll
    for (int rr = 0; rr < 4; ++rr) { m_[rb][rr] = -1e30f; l_[rb][rr] = 0.f; }
#pragma unroll
    for (int db = 0; db < 4; ++db) o_[rb][db] = fzero;
  }

  const int rsel = lane >> 3;
  const int csw = ((lane & 7) ^ rsel) << 4;

  auto stage = [&](int buf, int kv0) {
#pragma unroll
    for (int s = 0; s < 2; ++s) {
      const int row = s * 32 + wave * 8 + rsel;
      gl_lds16((const char*)Kb + (size_t)(kv0 + row) * (size_t)(kst * 2) + csw,
               (char*)&Ks[buf][0] + s * 4096 + wave * 1024);
      gl_lds16((const char*)Vtb + (size_t)row * 2048 + (size_t)kv0 * 2 + csw,
               (char*)&Vs[buf][0] + s * 4096 + wave * 1024);
    }
  };

  const int kv_end = CAUSAL ? (qt + 128) : 1024;
  const int nt = kv_end >> 6;

  stage(0, 0);
  __syncthreads();
  int cur = 0;
  for (int tt = 0; tt < nt; ++tt) {
    const int kv0 = tt * 64;
    if (tt + 1 < nt) stage(cur ^ 1, kv0 + 64);

    const char* ksb = (const char*)&Ks[cur][0];
    const char* vsb = (const char*)&Vs[cur][0];

    short8x kf[4][2];
#pragma unroll
    for (int nb = 0; nb < 4; ++nb) {
      const int row = nb * 16 + lr;
#pragma unroll
      for (int kk = 0; kk < 2; ++kk)
        kf[nb][kk] = *(const short8x*)(ksb + row * 128 + (((kk * 4 + lkg) ^ sw) << 4));
    }

#pragma unroll
    for (int rb = 0; rb < 2; ++rb) {
      f32x4 s[4];
#pragma unroll
      for (int nb = 0; nb < 4; ++nb) {
        s[nb] = __builtin_amdgcn_mfma_f32_16x16x32_bf16(qf[rb][0], kf[nb][0], fzero, 0, 0, 0);
        s[nb] = __builtin_amdgcn_mfma_f32_16x16x32_bf16(qf[rb][1], kf[nb][1], s[nb], 0, 0, 0);
      }
      if (CAUSAL && (kv0 + 63 > qw + rb * 16)) {
#pragma unroll
        for (int rr = 0; rr < 4; ++rr) {
          const int qg = qw + rb * 16 + lkg * 4 + rr;
#pragma unroll
          for (int nb = 0; nb < 4; ++nb)
            if (kv0 + nb * 16 + lr > qg) s[nb][rr] = -1e30f;
        }
      }
#pragma unroll
      for (int rr = 0; rr < 4; ++rr) {
        float mx = fmaxf(fmaxf(s[0][rr], s[1][rr]), fmaxf(s[2][rr], s[3][rr]));
#pragma unroll
        for (int d = 1; d < 16; d <<= 1) mx = fmaxf(mx, __shfl_xor(mx, d, 16));
        const float mold = m_[rb][rr];
        const float mnew = fmaxf(mold, mx);
        float p[4];
#pragma unroll
        for (int nb = 0; nb < 4; ++nb) p[nb] = __expf(s[nb][rr] - mnew);
        float rsum = (p[0] + p[1]) + (p[2] + p[3]);
#pragma unroll
        for (int d = 1; d < 16; d <<= 1) rsum += __shfl_xor(rsum, d, 16);
        const float alpha = __expf(mold - mnew);
        m_[rb][rr] = mnew;
        l_[rb][rr] = l_[rb][rr] * alpha + rsum;
#pragma unroll
        for (int db = 0; db < 4; ++db) o_[rb][db][rr] *= alpha;
        const int prow = rb * 16 + lkg * 4 + rr;
#pragma unroll
        for (int nb = 0; nb < 4; ++nb)
          Ps[wave][prow * 72 + nb * 16 + lr] = f2bf(p[nb]);
      }
    }
    asm volatile("s_waitcnt lgkmcnt(0)" ::: "memory");

    short8x vF[4][2];
#pragma unroll
    for (int db = 0; db < 4; ++db) {
      const int row = db * 16 + lr;
#pragma unroll
      for (int kk = 0; kk < 2; ++kk)
        vF[db][kk] = *(const short8x*)(vsb + row * 128 + (((kk * 4 + lkg) ^ sw) << 4));
    }
#pragma unroll
    for (int rb = 0; rb < 2; ++rb) {
#pragma unroll
      for (int kk = 0; kk < 2; ++kk) {
        const short8x aP = *(const short8x*)((const char*)&Ps[wave][0] + (rb * 16 + lr) * 144 + kk * 64 + lkg * 16);
#pragma unroll
        for (int db = 0; db < 4; ++db)
          o_[rb][db] = __builtin_amdgcn_mfma_f32_16x16x32_bf16(aP, vF[db][kk], o_[rb][db], 0, 0, 0);
      }
    }
    __syncthreads();
    cur ^= 1;
  }

#pragma unroll
  for (int rb = 0; rb < 2; ++rb)
#pragma unroll
    for (int rr = 0; rr < 4; ++rr) {
      const float inv = 1.0f / l_[rb][rr];
      const int qg = qw + rb * 16 + lkg * 4 + rr;
#pragma unroll
      for (int db = 0; db < 4; ++db)
        Ob[(size_t)qg * 1024 + db * 16 + lr] = f2bf(o_[rb][db][rr] * inv);
    }
}

// ---------------- LayerNorm(X [+X2] [+bias] + R) ----------------
__global__ __launch_bounds__(256) void ln_res(const float* __restrict__ X, const float* __restrict__ X2,
                                              const float* __restrict__ bias, const float* __restrict__ R,
                                              const float* __restrict__ gam, const float* __restrict__ bet,
                                              float* __restrict__ oF, u16* __restrict__ oB) {
  __shared__ float red[8];
  const int row = blockIdx.x, t = threadIdx.x;
  const int wave = t >> 6, lane = t & 63;
  const size_t off = (size_t)row * 1024 + t * 4;
  f4 x = *(const f4*)(X + off);
  f4 r = *(const f4*)(R + off);
  float v[4];
#pragma unroll
  for (int j = 0; j < 4; ++j) v[j] = x[j] + r[j];
  if (X2) {
    f4 x2 = *(const f4*)(X2 + off);
#pragma unroll
    for (int j = 0; j < 4; ++j) v[j] += x2[j];
  }
  if (bias) {
    f4 bb = *(const f4*)(bias + t * 4);
#pragma unroll
    for (int j = 0; j < 4; ++j) v[j] += bb[j];
  }
  float s = 0.f, sq = 0.f;
#pragma unroll
  for (int j = 0; j < 4; ++j) { s += v[j]; sq += v[j] * v[j]; }
#pragma unroll
  for (int d = 1; d < 64; d <<= 1) {
    s += __shfl_xor(s, d, 64);
    sq += __shfl_xor(sq, d, 64);
  }
  if (lane == 0) { red[wave * 2] = s; red[wave * 2 + 1] = sq; }
  __syncthreads();
  s = red[0] + red[2] + red[4] + red[6];
  sq = red[1] + red[3] + red[5] + red[7];
  const float mu = s * (1.0f / 1024.0f);
  const float var = sq * (1.0f / 1024.0f) - mu * mu;
  const float rs = rsqrtf(var + 1e-5f);
  f4 g4 = *(const f4*)(gam + t * 4);
  f4 b4 = *(const f4*)(bet + t * 4);
  f4 y;
#pragma unroll
  for (int j = 0; j < 4; ++j) y[j] = (v[j] - mu) * rs * g4[j] + b4[j];
  *(f4*)(oF + off) = y;
  if (oB) {
    u16x4 yb;
#pragma unroll
    for (int j = 0; j < 4; ++j) yb[j] = f2bf(y[j]);
    *(u16x4*)(oB + off) = yb;
  }
}

// ---------------- launcher ----------------
extern "C" void kernel_launch(void* const* d_in, const int* in_sizes, int n_in,
                              void* d_out, int out_size, void* d_ws, size_t ws_size,
                              hipStream_t stream) {
  const float* embeds = (const float*)d_in[0];
  const float* enc = (const float*)d_in[1];
  const float* wq1 = (const float*)d_in[2];
  const float* wk1 = (const float*)d_in[3];
  const float* wv1 = (const float*)d_in[4];
  const float* wo1 = (const float*)d_in[5];
  const float* wq2 = (const float*)d_in[6];
  const float* wk2 = (const float*)d_in[7];
  const float* wv2 = (const float*)d_in[8];
  const float* wo2 = (const float*)d_in[9];
  const float* ln1g = (const float*)d_in[10];
  const float* ln1b = (const float*)d_in[11];
  const float* ln2g = (const float*)d_in[12];
  const float* ln2b = (const float*)d_in[13];
  const float* ln3g = (const float*)d_in[14];
  const float* ln3b = (const float*)d_in[15];
  const float* w1 = (const float*)d_in[16];
  const float* b1 = (const float*)d_in[17];
  const float* w2 = (const float*)d_in[18];
  const float* b2 = (const float*)d_in[19];
  float* out = (float*)d_out;
  char* ws = (char*)d_ws;
  const size_t MB = (size_t)1 << 20;

  u16* QKV = (u16*)(ws + 0 * MB);      // 48MB [8192, 3072] bf16 (layer1 QKV; layer2 Q cols 0..1023)
  u16* Vtb = (u16*)(ws + 48 * MB);     // 16MB
  u16* Hd = (u16*)(ws + 64 * MB);      // 16MB heads
  float* Of = (float*)(ws + 80 * MB);  // 32MB f32 gemm out
  u16* ebf = (u16*)(ws + 112 * MB);    // 16MB (x1 bf16 later; dead by FF2)
  u16* encb = (u16*)(ws + 128 * MB);   // 16MB (x2 bf16 later)
  float* x1f = (float*)(ws + 144 * MB);
  float* x2f = (float*)(ws + 176 * MB);  // also KV2 staging (dead until LN2 writes it)
  u16* Wq1t = (u16*)(ws + 208 * MB);   // z0..z2: Wq1/Wk1/Wv1 (fused QKV1)
  u16* Wq2t = (u16*)(ws + 214 * MB);   // z3
  u16* Wk2t = (u16*)(ws + 216 * MB);   // z4,z5: Wk2/Wv2 (fused KV2)
  u16* Wo1b = (u16*)(ws + 220 * MB);
  u16* Wo2b = (u16*)(ws + 222 * MB);
  u16* W1b = (u16*)(ws + 224 * MB);  // 8MB
  u16* W2b = (u16*)(ws + 232 * MB);  // 8MB, end = 240MB
  u16* x1b = ebf;
  u16* x2b = encb;
  u16* Hff = (u16*)(ws + 0 * MB);  // 64MB, reuses QKV/Vtb after attn2

  u16* KV2 = (u16*)(ws + 176 * MB);     // 32MB [8192, 2048] bf16, layer-2 K|V
  float* P3 = (float*)(ws + 112 * MB);  // 32MB FF2 z=1 partial (ebf/x1b dead by FF2)
  const long long ZC = (long long)8192 * 1024;

  dim3 blk(256);

  cast_bf16_2<<<dim3(8192, 2), blk, 0, stream>>>(embeds, enc, ebf, encb);
  cast_wqkv6<<<dim3(16, 16, 6), blk, 0, stream>>>(wq1, wk1, wv1, wq2, wk2, wv2, Wq1t);
  cast_bf16_2<<<dim3(1024, 2), blk, 0, stream>>>(wo1, wo2, Wo1b, Wo2b);
  cast_bf16_2<<<dim3(4096, 2), blk, 0, stream>>>(w1, w2, W1b, W2b);

  // ---- masked self-attention + LN1 ----
  gemm_bt<5><<<dim3(24, 64), blk, 0, stream>>>(ebf, Wq1t, QKV, nullptr, 1024, 1024, 3072, 0);
  transpose_v<<<dim3(32, 128), blk, 0, stream>>>(QKV, Vtb, 3072, 2048);
  flash_attn<1><<<dim3(8, 128), blk, 0, stream>>>(QKV, QKV + 1024, Vtb, Hd, 3072, 3072);
  gemm_bt<1><<<dim3(8, 64), blk, 0, stream>>>(Hd, Wo1b, Of, nullptr, 1024, 1024, 1024, 0);
  ln_res<<<8192, blk, 0, stream>>>(Of, nullptr, nullptr, embeds, ln1g, ln1b, x1f, x1b);

  // ---- cross-attention + LN2 ----
  gemm_q2kv2<<<dim3(24, 64), blk, 0, stream>>>(x1b, Wq2t, QKV, encb, Wk2t, KV2);
  transpose_v<<<dim3(32, 128), blk, 0, stream>>>(KV2, Vtb, 2048, 1024);
  flash_attn<0><<<dim3(8, 128), blk, 0, stream>>>(QKV, KV2, Vtb, Hd, 3072, 2048);
  gemm_bt<1><<<dim3(8, 64), blk, 0, stream>>>(Hd, Wo2b, Of, nullptr, 1024, 1024, 1024, 0);
  ln_res<<<8192, blk, 0, stream>>>(Of, nullptr, nullptr, x1f, ln2g, ln2b, x2f, x2b);

  // ---- feed-forward + LN3 ----
  gemm_bt<2><<<dim3(32, 64), blk, 0, stream>>>(x2b, W1b, Hff, b1, 1024, 1024, 4096, 0);
  gemm_bt<1><<<dim3(8, 64, 2), blk, 0, stream>>>(Hff, W2b, Of, nullptr, 4096, 2048, 1024, ZC);
  ln_res<<<8192, blk, 0, stream>>>(Of, P3, b2, x2f, ln3g, ln3b, out, nullptr);
}

// Round 15
// 698.731 us; speedup vs baseline: 1.0237x; 1.0237x over previous
//
#include <hip/hip_runtime.h>
#include <cstdint>
#include <cstddef>

typedef unsigned short u16;
typedef __attribute__((ext_vector_type(4))) float f32x4;
typedef __attribute__((ext_vector_type(4))) float f4;
typedef __attribute__((ext_vector_type(8))) short short8x;
typedef __attribute__((ext_vector_type(4))) u16 u16x4;
typedef __attribute__((ext_vector_type(8))) u16 u16x8;

#define DEV static __device__ __forceinline__

DEV void gl_lds16(const void* g, void* l) {
  __builtin_amdgcn_global_load_lds(
      (const __attribute__((address_space(1))) unsigned int*)g,
      (__attribute__((address_space(3))) unsigned int*)l, 16, 0, 0);
}

DEV u16 f2bf(float f) {
  unsigned u = __float_as_uint(f);
  u += 0x7fffu + ((u >> 16) & 1u);
  return (u16)(u >> 16);
}

// ---------------- cast / pack kernels ----------------

__global__ __launch_bounds__(256) void cast_bf16_2(const float* __restrict__ X0, const float* __restrict__ X1,
                                                   u16* __restrict__ Y0, u16* __restrict__ Y1) {
  const float* X = blockIdx.y ? X1 : X0;
  u16* Y = blockIdx.y ? Y1 : Y0;
  size_t i = ((size_t)blockIdx.x * 256 + threadIdx.x) * 4;
  f4 v = *(const f4*)(X + i);
  u16x4 y;
#pragma unroll
  for (int j = 0; j < 4; ++j) y[j] = f2bf(v[j]);
  *(u16x4*)(Y + i) = y;
}

// 6x wq [H,D,DH] f32 -> Wt [H*DH, D] bf16 (B^T form), dsts contiguous at Wbase + z*1M elems
__global__ __launch_bounds__(256) void cast_wqkv6(const float* __restrict__ W0, const float* __restrict__ W1,
                                                  const float* __restrict__ W2, const float* __restrict__ W3,
                                                  const float* __restrict__ W4, const float* __restrict__ W5,
                                                  u16* __restrict__ Wbase) {
  __shared__ float tile[64][65];
  const int t = threadIdx.x;
  const int h = blockIdx.y;
  const int z = blockIdx.z;
  const int d0 = blockIdx.x * 64;
  const float* W = (z == 0) ? W0 : (z == 1) ? W1 : (z == 2) ? W2 : (z == 3) ? W3 : (z == 4) ? W4 : W5;
  u16* Wt = Wbase + (size_t)z * (1024 * 1024);
  const float* Wb = W + (size_t)h * (1024 * 64);
  const int di = t >> 2;
  const int j0 = (t & 3) * 16;
#pragma unroll
  for (int c = 0; c < 4; ++c) {
    f4 v = *(const f4*)(Wb + (size_t)(d0 + di) * 64 + j0 + c * 4);
#pragma unroll
    for (int j = 0; j < 4; ++j) tile[di][j0 + c * 4 + j] = v[j];
  }
  __syncthreads();
  const int k = t >> 2;
  const int dd0 = (t & 3) * 16;
  u16x8 o0, o1;
#pragma unroll
  for (int u = 0; u < 8; ++u) o0[u] = f2bf(tile[dd0 + u][k]);
#pragma unroll
  for (int u = 0; u < 8; ++u) o1[u] = f2bf(tile[dd0 + 8 + u][k]);
  u16* dst = Wt + (size_t)(h * 64 + k) * 1024 + d0 + dd0;
  *(u16x8*)(dst) = o0;
  *(u16x8*)(dst + 8) = o1;
}

// V columns of src [B,S,vstride] bf16 -> Vt [B*H, DH, S] bf16
__global__ __launch_bounds__(256) void transpose_v(const u16* __restrict__ V, u16* __restrict__ Vt,
                                                   int vstride, int voff) {
  __shared__ u16 tile[32][72];
  const int t = threadIdx.x;
  const int bh = blockIdx.y;
  const int s0 = blockIdx.x * 32;
  const u16* Vb = V + (size_t)(bh >> 4) * (1024 * (size_t)vstride) + voff + (bh & 15) * 64;
  const int si = t >> 3, d0 = (t & 7) * 8;
  u16x8 val = *(const u16x8*)(Vb + (size_t)(s0 + si) * vstride + d0);
#pragma unroll
  for (int u = 0; u < 8; ++u) tile[si][d0 + u] = val[u];
  __syncthreads();
  const int d = t >> 2, sj0 = (t & 3) * 8;
  u16x8 o;
#pragma unroll
  for (int u = 0; u < 8; ++u) o[u] = tile[sj0 + u][d];
  *(u16x8*)(Vt + (size_t)bh * (64 * 1024) + (size_t)d * 1024 + s0 + sj0) = o;
}

// ---------------- GEMM 128x128, BK=32, 2-phase, static ping-pong (R7-verified) ----------------
// EPI: 0=bf16, 1=f32, 2=bias+GELU->bf16, 4=scale(1/8)->bf16, 5=QKV scale cols<1024
template <int EPI>
__global__ __launch_bounds__(256, 3) void gemm_bt(const u16* __restrict__ A, const u16* __restrict__ Bt,
                                                  void* __restrict__ C, const float* __restrict__ bias,
                                                  int Krow, int Kit, int ldc, long long zC) {
  __shared__ u16 As0[128 * 32], Bs0[128 * 32];
  __shared__ u16 As1[128 * 32], Bs1[128 * 32];
  const int t = threadIdx.x;
  const int wave = t >> 6, lane = t & 63;
  const int lr = lane & 15, lkg = lane >> 4;
  const int swz = (lr >> 1) & 3;
  const int wr = (wave >> 1) * 64, wc = (wave & 1) * 64;

  const int gx = gridDim.x;
  const int nwg = gx * gridDim.y;
  const int flat = blockIdx.y * gx + blockIdx.x;
  const int wg = (flat & 7) * (nwg >> 3) + (flat >> 3);
  const int m0 = (wg / gx) * 128, n0 = (wg % gx) * 128;

  const int schunk = ((t & 3) ^ ((t >> 3) & 3)) << 4;
  const size_t rowb = (size_t)Krow * 2;
  const size_t rowskip = (size_t)64 * rowb;
  const size_t zoff = (size_t)blockIdx.z * (size_t)Kit * 2;
  const char* gA0 = (const char*)A + (size_t)(m0 + (t >> 2)) * rowb + zoff + schunk;
  const char* gA1 = gA0 + rowskip;
  const char* gB0 = (const char*)Bt + (size_t)(n0 + (t >> 2)) * rowb + zoff + schunk;
  const char* gB1 = gB0 + rowskip;

  char* dA0 = (char*)As0 + wave * 1024;
  char* dB0 = (char*)Bs0 + wave * 1024;
  char* dA1 = (char*)As1 + wave * 1024;
  char* dB1 = (char*)Bs1 + wave * 1024;

  const int aoff = (wr + lr) * 64 + ((lkg ^ swz) << 4);
  const int boff = (wc + lr) * 64 + ((lkg ^ swz) << 4);
  const char* rA0 = (const char*)As0 + aoff;
  const char* rB0 = (const char*)Bs0 + boff;
  const char* rA1 = (const char*)As1 + aoff;
  const char* rB1 = (const char*)Bs1 + boff;

  const f32x4 fzero = {0.f, 0.f, 0.f, 0.f};
  f32x4 acc[4][4];
#pragma unroll
  for (int m = 0; m < 4; ++m)
#pragma unroll
    for (int n = 0; n < 4; ++n) acc[m][n] = fzero;

  auto compute = [&](const char* rA, const char* rB) {
    short8x aF[4], bF[4];
#pragma unroll
    for (int m = 0; m < 4; ++m) aF[m] = *(const short8x*)(rA + m * 1024);
#pragma unroll
    for (int n = 0; n < 4; ++n) bF[n] = *(const short8x*)(rB + n * 1024);
#pragma unroll
    for (int m = 0; m < 4; ++m)
#pragma unroll
      for (int n = 0; n < 4; ++n)
        acc[m][n] = __builtin_amdgcn_mfma_f32_16x16x32_bf16(aF[m], bF[n], acc[m][n], 0, 0, 0);
  };

  gl_lds16(gA0, dA0); gl_lds16(gA1, dA0 + 4096);
  gl_lds16(gB0, dB0); gl_lds16(gB1, dB0 + 4096);
  gA0 += 64; gA1 += 64; gB0 += 64; gB1 += 64;
  __syncthreads();

  const int nk2 = Kit >> 6;
  for (int p = 0; p < nk2; ++p) {
    gl_lds16(gA0, dA1); gl_lds16(gA1, dA1 + 4096);
    gl_lds16(gB0, dB1); gl_lds16(gB1, dB1 + 4096);
    gA0 += 64; gA1 += 64; gB0 += 64; gB1 += 64;
    compute(rA0, rB0);
    __syncthreads();
    if (p + 1 < nk2) {
      gl_lds16(gA0, dA0); gl_lds16(gA1, dA0 + 4096);
      gl_lds16(gB0, dB0); gl_lds16(gB1, dB0 + 4096);
    }
    gA0 += 64; gA1 += 64; gB0 += 64; gB1 += 64;
    compute(rA1, rB1);
    __syncthreads();
  }

#pragma unroll
  for (int m = 0; m < 4; ++m) {
#pragma unroll
    for (int rr = 0; rr < 4; ++rr) {
      const int gm = m0 + wr + m * 16 + lkg * 4 + rr;
#pragma unroll
      for (int n = 0; n < 4; ++n) {
        const int gn = n0 + wc + n * 16 + lr;
        float v = acc[m][n][rr];
        if (EPI == 2) v += bias[gn];
        if (EPI == 2) v = 0.5f * v * (1.0f + erff(v * 0.70710678118654752f));
        if (EPI == 4) v *= 0.125f;
        if (EPI == 5 && gn < 1024) v *= 0.125f;
        if (EPI == 1)
          ((float*)C)[(size_t)blockIdx.z * zC + (size_t)gm * ldc + gn] = v;
        else
          ((u16*)C)[(size_t)gm * ldc + gn] = f2bf(v);
      }
    }
  }
}

// ---- merged Q2 (scale 1/8 -> QKV ldc 3072) + KV2 (plain -> KV2buf ldc 2048) ----
// grid (24, 64): swizzled flat < 512 -> Q2 (gx 8), else KV2 (gx 16). K = 1024.
__global__ __launch_bounds__(256, 3) void gemm_q2kv2(const u16* __restrict__ A1, const u16* __restrict__ B1,
                                                     u16* __restrict__ C1, const u16* __restrict__ A2,
                                                     const u16* __restrict__ B2, u16* __restrict__ C2) {
  __shared__ u16 As0[128 * 32], Bs0[128 * 32];
  __shared__ u16 As1[128 * 32], Bs1[128 * 32];
  const int t = threadIdx.x;
  const int wave = t >> 6, lane = t & 63;
  const int lr = lane & 15, lkg = lane >> 4;
  const int swz = (lr >> 1) & 3;
  const int wr = (wave >> 1) * 64, wc = (wave & 1) * 64;

  const int nwg = 24 * 64;
  const int flat = blockIdx.y * 24 + blockIdx.x;
  const int wg = (flat & 7) * (nwg >> 3) + (flat >> 3);

  const int sub = (wg >= 512);
  const int wl = sub ? (wg - 512) : wg;
  const int gxl = sub ? 16 : 8;
  const int m0 = (wl / gxl) * 128, n0 = (wl % gxl) * 128;
  const u16* A = sub ? A2 : A1;
  const u16* Bt = sub ? B2 : B1;
  u16* C = sub ? C2 : C1;
  const int ldc = sub ? 2048 : 3072;
  const float scale = sub ? 1.0f : 0.125f;

  const int schunk = ((t & 3) ^ ((t >> 3) & 3)) << 4;
  const size_t rowb = 2048;  // K=1024 bf16
  const size_t rowskip = (size_t)64 * rowb;
  const char* gA0 = (const char*)A + (size_t)(m0 + (t >> 2)) * rowb + schunk;
  const char* gA1 = gA0 + rowskip;
  const char* gB0 = (const char*)Bt + (size_t)(n0 + (t >> 2)) * rowb + schunk;
  const char* gB1 = gB0 + rowskip;

  char* dA0 = (char*)As0 + wave * 1024;
  char* dB0 = (char*)Bs0 + wave * 1024;
  char* dA1 = (char*)As1 + wave * 1024;
  char* dB1 = (char*)Bs1 + wave * 1024;

  const int aoff = (wr + lr) * 64 + ((lkg ^ swz) << 4);
  const int boff = (wc + lr) * 64 + ((lkg ^ swz) << 4);
  const char* rA0 = (const char*)As0 + aoff;
  const char* rB0 = (const char*)Bs0 + boff;
  const char* rA1 = (const char*)As1 + aoff;
  const char* rB1 = (const char*)Bs1 + boff;

  const f32x4 fzero = {0.f, 0.f, 0.f, 0.f};
  f32x4 acc[4][4];
#pragma unroll
  for (int m = 0; m < 4; ++m)
#pragma unroll
    for (int n = 0; n < 4; ++n) acc[m][n] = fzero;

  auto compute = [&](const char* rA, const char* rB) {
    short8x aF[4], bF[4];
#pragma unroll
    for (int m = 0; m < 4; ++m) aF[m] = *(const short8x*)(rA + m * 1024);
#pragma unroll
    for (int n = 0; n < 4; ++n) bF[n] = *(const short8x*)(rB + n * 1024);
#pragma unroll
    for (int m = 0; m < 4; ++m)
#pragma unroll
      for (int n = 0; n < 4; ++n)
        acc[m][n] = __builtin_amdgcn_mfma_f32_16x16x32_bf16(aF[m], bF[n], acc[m][n], 0, 0, 0);
  };

  gl_lds16(gA0, dA0); gl_lds16(gA1, dA0 + 4096);
  gl_lds16(gB0, dB0); gl_lds16(gB1, dB0 + 4096);
  gA0 += 64; gA1 += 64; gB0 += 64; gB1 += 64;
  __syncthreads();

  for (int p = 0; p < 16; ++p) {
    gl_lds16(gA0, dA1); gl_lds16(gA1, dA1 + 4096);
    gl_lds16(gB0, dB1); gl_lds16(gB1, dB1 + 4096);
    gA0 += 64; gA1 += 64; gB0 += 64; gB1 += 64;
    compute(rA0, rB0);
    __syncthreads();
    if (p + 1 < 16) {
      gl_lds16(gA0, dA0); gl_lds16(gA1, dA0 + 4096);
      gl_lds16(gB0, dB0); gl_lds16(gB1, dB0 + 4096);
    }
    gA0 += 64; gA1 += 64; gB0 += 64; gB1 += 64;
    compute(rA1, rB1);
    __syncthreads();
  }

#pragma unroll
  for (int m = 0; m < 4; ++m) {
#pragma unroll
    for (int rr = 0; rr < 4; ++rr) {
      const int gm = m0 + wr + m * 16 + lkg * 4 + rr;
#pragma unroll
      for (int n = 0; n < 4; ++n) {
        const int gn = n0 + wc + n * 16 + lr;
        C[(size_t)gm * ldc + gn] = f2bf(acc[m][n][rr] * scale);
      }
    }
  }
}

// ---------------- flash attention (verified; separate Q/K strides, causal longest-first) ----------------
template <int CAUSAL>
__global__ __launch_bounds__(256, 3) void flash_attn(const u16* __restrict__ Q, const u16* __restrict__ Kk,
                                                     const u16* __restrict__ Vt, u16* __restrict__ O,
                                                     int qst, int kst) {
  __shared__ u16 Ks[2][64 * 64];
  __shared__ u16 Vs[2][64 * 64];
  __shared__ u16 Ps[4][32 * 72];
  const int t = threadIdx.x;
  const int wave = t >> 6, lane = t & 63;
  const int lr = lane & 15, lkg = lane >> 4, lk = lkg * 8;
  const int sw = lr & 7;
  const int bh = blockIdx.y;
  const u16* Qb = Q + (size_t)(bh >> 4) * (1024 * (size_t)qst) + (bh & 15) * 64;
  const u16* Kb = Kk + (size_t)(bh >> 4) * (1024 * (size_t)kst) + (bh & 15) * 64;
  const u16* Vtb = Vt + (size_t)bh * (64 * 1024);
  u16* Ob = O + (size_t)(bh >> 4) * (1024 * 1024) + (bh & 15) * 64;
  const int qt = (gridDim.x - 1 - blockIdx.x) * 128;
  const int qw = qt + wave * 32;

  const f32x4 fzero = {0.f, 0.f, 0.f, 0.f};
  short8x qf[2][2];
#pragma unroll
  for (int rb = 0; rb < 2; ++rb)
#pragma unroll
    for (int kk = 0; kk < 2; ++kk)
      qf[rb][kk] = *(const short8x*)(Qb + (size_t)(qw + rb * 16 + lr) * qst + kk * 32 + lk);

  float m_[2][4], l_[2][4];
  f32x4 o_[2][4];
#pragma unroll
  for (int rb = 0; rb < 2; ++rb) {
#pragma unroll
    for (int rr = 0; rr < 4; ++rr) { m_[rb][rr] = -1e30f; l_[rb][rr] = 0.f; }
#pragma unroll
    for (int db = 0; db < 4; ++db) o_[rb][db] = fzero;
  }

  const int rsel = lane >> 3;
  const int csw = ((lane & 7) ^ rsel) << 4;

  auto stage = [&](int buf, int kv0) {
#pragma unroll
    for (int s = 0; s < 2; ++s) {
      const int row = s * 32 + wave * 8 + rsel;
      gl_lds16((const char*)Kb + (size_t)(kv0 + row) * (size_t)(kst * 2) + csw,
               (char*)&Ks[buf][0] + s * 4096 + wave * 1024);
      gl_lds16((const char*)Vtb + (size_t)row * 2048 + (size_t)kv0 * 2 + csw,
               (char*)&Vs[buf][0] + s * 4096 + wave * 1024);
    }
  };

  const int kv_end = CAUSAL ? (qt + 128) : 1024;
  const int nt = kv_end >> 6;

  stage(0, 0);
  __syncthreads();
  int cur = 0;
  for (int tt = 0; tt < nt; ++tt) {
    const int kv0 = tt * 64;
    if (tt + 1 < nt) stage(cur ^ 1, kv0 + 64);

    const char* ksb = (const char*)&Ks[cur][0];
    const char* vsb = (const char*)&Vs[cur][0];

    short8x kf[4][2];
#pragma unroll
    for (int nb = 0; nb < 4; ++nb) {
      const int row = nb * 16 + lr;
#pragma unroll
      for (int kk = 0; kk < 2; ++kk)
        kf[nb][kk] = *(const short8x*)(ksb + row * 128 + (((kk * 4 + lkg) ^ sw) << 4));
    }

#pragma unroll
    for (int rb = 0; rb < 2; ++rb) {
      f32x4 s[4];
#pragma unroll
      for (int nb = 0; nb < 4; ++nb) {
        s[nb] = __builtin_amdgcn_mfma_f32_16x16x32_bf16(qf[rb][0], kf[nb][0], fzero, 0, 0, 0);
        s[nb] = __builtin_amdgcn_mfma_f32_16x16x32_bf16(qf[rb][1], kf[nb][1], s[nb], 0, 0, 0);
      }
      if (CAUSAL && (kv0 + 63 > qw + rb * 16)) {
#pragma unroll
        for (int rr = 0; rr < 4; ++rr) {
          const int qg = qw + rb * 16 + lkg * 4 + rr;
#pragma unroll
          for (int nb = 0; nb < 4; ++nb)
            if (kv0 + nb * 16 + lr > qg) s[nb][rr] = -1e30f;
        }
      }
#pragma unroll
      for (int rr = 0; rr < 4; ++rr) {
        float mx = fmaxf(fmaxf(s[0][rr], s[1][rr]), fmaxf(s[2][rr], s[3][rr]));
#pragma unroll
        for (int d = 1; d < 16; d <<= 1) mx = fmaxf(mx, __shfl_xor(mx, d, 16));
        const float mold = m_[rb][rr];
        const float mnew = fmaxf(mold, mx);
        float p[4];
#pragma unroll
        for (int nb = 0; nb < 4; ++nb) p[nb] = __expf(s[nb][rr] - mnew);
        float rsum = (p[0] + p[1]) + (p[2] + p[3]);
#pragma unroll
        for (int d = 1; d < 16; d <<= 1) rsum += __shfl_xor(rsum, d, 16);
        const float alpha = __expf(mold - mnew);
        m_[rb][rr] = mnew;
        l_[rb][rr] = l_[rb][rr] * alpha + rsum;
#pragma unroll
        for (int db = 0; db < 4; ++db) o_[rb][db][rr] *= alpha;
        const int prow = rb * 16 + lkg * 4 + rr;
#pragma unroll
        for (int nb = 0; nb < 4; ++nb)
          Ps[wave][prow * 72 + nb * 16 + lr] = f2bf(p[nb]);
      }
    }
    asm volatile("s_waitcnt lgkmcnt(0)" ::: "memory");

    short8x vF[4][2];
#pragma unroll
    for (int db = 0; db < 4; ++db) {
      const int row = db * 16 + lr;
#pragma unroll
      for (int kk = 0; kk < 2; ++kk)
        vF[db][kk] = *(const short8x*)(vsb + row * 128 + (((kk * 4 + lkg) ^ sw) << 4));
    }
#pragma unroll
    for (int rb = 0; rb < 2; ++rb) {
#pragma unroll
      for (int kk = 0; kk < 2; ++kk) {
        const short8x aP = *(const short8x*)((const char*)&Ps[wave][0] + (rb * 16 + lr) * 144 + kk * 64 + lkg * 16);
#pragma unroll
        for (int db = 0; db < 4; ++db)
          o_[rb][db] = __builtin_amdgcn_mfma_f32_16x16x32_bf16(aP, vF[db][kk], o_[rb][db], 0, 0, 0);
      }
    }
    __syncthreads();
    cur ^= 1;
  }

#pragma unroll
  for (int rb = 0; rb < 2; ++rb)
#pragma unroll
    for (int rr = 0; rr < 4; ++rr) {
      const float inv = 1.0f / l_[rb][rr];
      const int qg = qw + rb * 16 + lkg * 4 + rr;
#pragma unroll
      for (int db = 0; db < 4; ++db)
        Ob[(size_t)qg * 1024 + db * 16 + lr] = f2bf(o_[rb][db][rr] * inv);
    }
}

// ---------------- LayerNorm(X [+X2] [+bias] + R) ----------------
__global__ __launch_bounds__(256) void ln_res(const float* __restrict__ X, const float* __restrict__ X2,
                                              const float* __restrict__ bias, const float* __restrict__ R,
                                              const float* __restrict__ gam, const float* __restrict__ bet,
                                              float* __restrict__ oF, u16* __restrict__ oB) {
  __shared__ float red[8];
  const int row = blockIdx.x, t = threadIdx.x;
  const int wave = t >> 6, lane = t & 63;
  const size_t off = (size_t)row * 1024 + t * 4;
  f4 x = *(const f4*)(X + off);
  f4 r = *(const f4*)(R + off);
  float v[4];
#pragma unroll
  for (int j = 0; j < 4; ++j) v[j] = x[j] + r[j];
  if (X2) {
    f4 x2 = *(const f4*)(X2 + off);
#pragma unroll
    for (int j = 0; j < 4; ++j) v[j] += x2[j];
  }
  if (bias) {
    f4 bb = *(const f4*)(bias + t * 4);
#pragma unroll
    for (int j = 0; j < 4; ++j) v[j] += bb[j];
  }
  float s = 0.f, sq = 0.f;
#pragma unroll
  for (int j = 0; j < 4; ++j) { s += v[j]; sq += v[j] * v[j]; }
#pragma unroll
  for (int d = 1; d < 64; d <<= 1) {
    s += __shfl_xor(s, d, 64);
    sq += __shfl_xor(sq, d, 64);
  }
  if (lane == 0) { red[wave * 2] = s; red[wave * 2 + 1] = sq; }
  __syncthreads();
  s = red[0] + red[2] + red[4] + red[6];
  sq = red[1] + red[3] + red[5] + red[7];
  const float mu = s * (1.0f / 1024.0f);
  const float var = sq * (1.0f / 1024.0f) - mu * mu;
  const float rs = rsqrtf(var + 1e-5f);
  f4 g4 = *(const f4*)(gam + t * 4);
  f4 b4 = *(const f4*)(bet + t * 4);
  f4 y;
#pragma unroll
  for (int j = 0; j < 4; ++j) y[j] = (v[j] - mu) * rs * g4[j] + b4[j];
  *(f4*)(oF + off) = y;
  if (oB) {
    u16x4 yb;
#pragma unroll
    for (int j = 0; j < 4; ++j) yb[j] = f2bf(y[j]);
    *(u16x4*)(oB + off) = yb;
  }
}

// ---------------- launcher ----------------
extern "C" void kernel_launch(void* const* d_in, const int* in_sizes, int n_in,
                              void* d_out, int out_size, void* d_ws, size_t ws_size,
                              hipStream_t stream) {
  const float* embeds = (const float*)d_in[0];
  const float* enc = (const float*)d_in[1];
  const float* wq1 = (const float*)d_in[2];
  const float* wk1 = (const float*)d_in[3];
  const float* wv1 = (const float*)d_in[4];
  const float* wo1 = (const float*)d_in[5];
  const float* wq2 = (const float*)d_in[6];
  const float* wk2 = (const float*)d_in[7];
  const float* wv2 = (const float*)d_in[8];
  const float* wo2 = (const float*)d_in[9];
  const float* ln1g = (const float*)d_in[10];
  const float* ln1b = (const float*)d_in[11];
  const float* ln2g = (const float*)d_in[12];
  const float* ln2b = (const float*)d_in[13];
  const float* ln3g = (const float*)d_in[14];
  const float* ln3b = (const float*)d_in[15];
  const float* w1 = (const float*)d_in[16];
  const float* b1 = (const float*)d_in[17];
  const float* w2 = (const float*)d_in[18];
  const float* b2 = (const float*)d_in[19];
  float* out = (float*)d_out;
  char* ws = (char*)d_ws;
  const size_t MB = (size_t)1 << 20;

  u16* QKV = (u16*)(ws + 0 * MB);      // 48MB [8192, 3072] bf16 (layer1 QKV; layer2 Q cols 0..1023)
  u16* Vtb = (u16*)(ws + 48 * MB);     // 16MB
  u16* Hd = (u16*)(ws + 64 * MB);      // 16MB heads
  float* Of = (float*)(ws + 80 * MB);  // 32MB f32 gemm out
  u16* ebf = (u16*)(ws + 112 * MB);    // 16MB (x1 bf16 later; dead by FF2)
  u16* encb = (u16*)(ws + 128 * MB);   // 16MB (x2 bf16 later)
  float* x1f = (float*)(ws + 144 * MB);
  float* x2f = (float*)(ws + 176 * MB);  // also KV2 staging (dead until LN2 writes it)
  u16* Wq1t = (u16*)(ws + 208 * MB);   // z0..z2: Wq1/Wk1/Wv1 (fused QKV1)
  u16* Wq2t = (u16*)(ws + 214 * MB);   // z3
  u16* Wk2t = (u16*)(ws + 216 * MB);   // z4,z5: Wk2/Wv2 (fused KV2)
  u16* Wo1b = (u16*)(ws + 220 * MB);
  u16* Wo2b = (u16*)(ws + 222 * MB);
  u16* W1b = (u16*)(ws + 224 * MB);  // 8MB
  u16* W2b = (u16*)(ws + 232 * MB);  // 8MB, end = 240MB
  u16* x1b = ebf;
  u16* x2b = encb;
  u16* Hff = (u16*)(ws + 0 * MB);  // 64MB, reuses QKV/Vtb after attn2

  u16* KV2 = (u16*)(ws + 176 * MB);     // 32MB [8192, 2048] bf16, layer-2 K|V
  float* P3 = (float*)(ws + 112 * MB);  // 32MB FF2 z=1 partial (ebf/x1b dead by FF2)
  const long long ZC = (long long)8192 * 1024;

  dim3 blk(256);

  cast_bf16_2<<<dim3(8192, 2), blk, 0, stream>>>(embeds, enc, ebf, encb);
  cast_wqkv6<<<dim3(16, 16, 6), blk, 0, stream>>>(wq1, wk1, wv1, wq2, wk2, wv2, Wq1t);
  cast_bf16_2<<<dim3(1024, 2), blk, 0, stream>>>(wo1, wo2, Wo1b, Wo2b);
  cast_bf16_2<<<dim3(4096, 2), blk, 0, stream>>>(w1, w2, W1b, W2b);

  // ---- masked self-attention + LN1 ----
  gemm_bt<5><<<dim3(24, 64), blk, 0, stream>>>(ebf, Wq1t, QKV, nullptr, 1024, 1024, 3072, 0);
  transpose_v<<<dim3(32, 128), blk, 0, stream>>>(QKV, Vtb, 3072, 2048);
  flash_attn<1><<<dim3(8, 128), blk, 0, stream>>>(QKV, QKV + 1024, Vtb, Hd, 3072, 3072);
  gemm_bt<1><<<dim3(8, 64), blk, 0, stream>>>(Hd, Wo1b, Of, nullptr, 1024, 1024, 1024, 0);
  ln_res<<<8192, blk, 0, stream>>>(Of, nullptr, nullptr, embeds, ln1g, ln1b, x1f, x1b);

  // ---- cross-attention + LN2 ----
  gemm_q2kv2<<<dim3(24, 64), blk, 0, stream>>>(x1b, Wq2t, QKV, encb, Wk2t, KV2);
  transpose_v<<<dim3(32, 128), blk, 0, stream>>>(KV2, Vtb, 2048, 1024);
  flash_attn<0><<<dim3(8, 128), blk, 0, stream>>>(QKV, KV2, Vtb, Hd, 3072, 2048);
  gemm_bt<1><<<dim3(8, 64), blk, 0, stream>>>(Hd, Wo2b, Of, nullptr, 1024, 1024, 1024, 0);
  ln_res<<<8192, blk, 0, stream>>>(Of, nullptr, nullptr, x1f, ln2g, ln2b, x2f, x2b);

  // ---- feed-forward + LN3 ----
  gemm_bt<2><<<dim3(32, 64), blk, 0, stream>>>(x2b, W1b, Hff, b1, 1024, 1024, 4096, 0);
  gemm_bt<1><<<dim3(8, 64, 2), blk, 0, stream>>>(Hff, W2b, Of, nullptr, 4096, 2048, 1024, ZC);
  ln_res<<<8192, blk, 0, stream>>>(Of, P3, b2, x2f, ln3g, ln3b, out, nullptr);
}

// Round 16
// 687.630 us; speedup vs baseline: 1.0402x; 1.0161x over previous
//
#include <hip/hip_runtime.h>
#include <cstdint>
#include <cstddef>

typedef unsigned short u16;
typedef __attribute__((ext_vector_type(4))) float f32x4;
typedef __attribute__((ext_vector_type(4))) float f4;
typedef __attribute__((ext_vector_type(8))) short short8x;
typedef __attribute__((ext_vector_type(4))) u16 u16x4;
typedef __attribute__((ext_vector_type(8))) u16 u16x8;

#define DEV static __device__ __forceinline__

DEV void gl_lds16(const void* g, void* l) {
  __builtin_amdgcn_global_load_lds(
      (const __attribute__((address_space(1))) unsigned int*)g,
      (__attribute__((address_space(3))) unsigned int*)l, 16, 0, 0);
}

DEV u16 f2bf(float f) {
  unsigned u = __float_as_uint(f);
  u += 0x7fffu + ((u >> 16) & 1u);
  return (u16)(u >> 16);
}
DEV float bf2f(u16 b) { return __uint_as_float(((unsigned)b) << 16); }

// ---------------- cast / pack kernels ----------------

__global__ __launch_bounds__(256) void cast_bf16_2(const float* __restrict__ X0, const float* __restrict__ X1,
                                                   u16* __restrict__ Y0, u16* __restrict__ Y1) {
  const float* X = blockIdx.y ? X1 : X0;
  u16* Y = blockIdx.y ? Y1 : Y0;
  size_t i = ((size_t)blockIdx.x * 256 + threadIdx.x) * 4;
  f4 v = *(const f4*)(X + i);
  u16x4 y;
#pragma unroll
  for (int j = 0; j < 4; ++j) y[j] = f2bf(v[j]);
  *(u16x4*)(Y + i) = y;
}

// 6x wq [H,D,DH] f32 -> Wt [H*DH, D] bf16 (B^T form), dsts contiguous at Wbase + z*1M elems
__global__ __launch_bounds__(256) void cast_wqkv6(const float* __restrict__ W0, const float* __restrict__ W1,
                                                  const float* __restrict__ W2, const float* __restrict__ W3,
                                                  const float* __restrict__ W4, const float* __restrict__ W5,
                                                  u16* __restrict__ Wbase) {
  __shared__ float tile[64][65];
  const int t = threadIdx.x;
  const int h = blockIdx.y;
  const int z = blockIdx.z;
  const int d0 = blockIdx.x * 64;
  const float* W = (z == 0) ? W0 : (z == 1) ? W1 : (z == 2) ? W2 : (z == 3) ? W3 : (z == 4) ? W4 : W5;
  u16* Wt = Wbase + (size_t)z * (1024 * 1024);
  const float* Wb = W + (size_t)h * (1024 * 64);
  const int di = t >> 2;
  const int j0 = (t & 3) * 16;
#pragma unroll
  for (int c = 0; c < 4; ++c) {
    f4 v = *(const f4*)(Wb + (size_t)(d0 + di) * 64 + j0 + c * 4);
#pragma unroll
    for (int j = 0; j < 4; ++j) tile[di][j0 + c * 4 + j] = v[j];
  }
  __syncthreads();
  const int k = t >> 2;
  const int dd0 = (t & 3) * 16;
  u16x8 o0, o1;
#pragma unroll
  for (int u = 0; u < 8; ++u) o0[u] = f2bf(tile[dd0 + u][k]);
#pragma unroll
  for (int u = 0; u < 8; ++u) o1[u] = f2bf(tile[dd0 + 8 + u][k]);
  u16* dst = Wt + (size_t)(h * 64 + k) * 1024 + d0 + dd0;
  *(u16x8*)(dst) = o0;
  *(u16x8*)(dst + 8) = o1;
}

// V columns of src [B,S,vstride] bf16 -> Vt [B*H, DH, S] bf16
__global__ __launch_bounds__(256) void transpose_v(const u16* __restrict__ V, u16* __restrict__ Vt,
                                                   int vstride, int voff) {
  __shared__ u16 tile[32][72];
  const int t = threadIdx.x;
  const int bh = blockIdx.y;
  const int s0 = blockIdx.x * 32;
  const u16* Vb = V + (size_t)(bh >> 4) * (1024 * (size_t)vstride) + voff + (bh & 15) * 64;
  const int si = t >> 3, d0 = (t & 7) * 8;
  u16x8 val = *(const u16x8*)(Vb + (size_t)(s0 + si) * vstride + d0);
#pragma unroll
  for (int u = 0; u < 8; ++u) tile[si][d0 + u] = val[u];
  __syncthreads();
  const int d = t >> 2, sj0 = (t & 3) * 8;
  u16x8 o;
#pragma unroll
  for (int u = 0; u < 8; ++u) o[u] = tile[sj0 + u][d];
  *(u16x8*)(Vt + (size_t)bh * (64 * 1024) + (size_t)d * 1024 + s0 + sj0) = o;
}

// ---------------- GEMM 128x128, BK=32, 2-phase, static ping-pong (R7-verified) ----------------
// EPI: 0=bf16 (+zC elem offset for split-K), 1=f32 (+zC), 2=bias+GELU->bf16,
//      4=scale(1/8)->bf16, 5=QKV scale cols<1024
template <int EPI>
__global__ __launch_bounds__(256, 3) void gemm_bt(const u16* __restrict__ A, const u16* __restrict__ Bt,
                                                  void* __restrict__ C, const float* __restrict__ bias,
                                                  int Krow, int Kit, int ldc, long long zC) {
  __shared__ u16 As0[128 * 32], Bs0[128 * 32];
  __shared__ u16 As1[128 * 32], Bs1[128 * 32];
  const int t = threadIdx.x;
  const int wave = t >> 6, lane = t & 63;
  const int lr = lane & 15, lkg = lane >> 4;
  const int swz = (lr >> 1) & 3;
  const int wr = (wave >> 1) * 64, wc = (wave & 1) * 64;

  const int gx = gridDim.x;
  const int nwg = gx * gridDim.y;
  const int flat = blockIdx.y * gx + blockIdx.x;
  const int wg = (flat & 7) * (nwg >> 3) + (flat >> 3);
  const int m0 = (wg / gx) * 128, n0 = (wg % gx) * 128;

  const int schunk = ((t & 3) ^ ((t >> 3) & 3)) << 4;
  const size_t rowb = (size_t)Krow * 2;
  const size_t rowskip = (size_t)64 * rowb;
  const size_t zoff = (size_t)blockIdx.z * (size_t)Kit * 2;
  const char* gA0 = (const char*)A + (size_t)(m0 + (t >> 2)) * rowb + zoff + schunk;
  const char* gA1 = gA0 + rowskip;
  const char* gB0 = (const char*)Bt + (size_t)(n0 + (t >> 2)) * rowb + zoff + schunk;
  const char* gB1 = gB0 + rowskip;

  char* dA0 = (char*)As0 + wave * 1024;
  char* dB0 = (char*)Bs0 + wave * 1024;
  char* dA1 = (char*)As1 + wave * 1024;
  char* dB1 = (char*)Bs1 + wave * 1024;

  const int aoff = (wr + lr) * 64 + ((lkg ^ swz) << 4);
  const int boff = (wc + lr) * 64 + ((lkg ^ swz) << 4);
  const char* rA0 = (const char*)As0 + aoff;
  const char* rB0 = (const char*)Bs0 + boff;
  const char* rA1 = (const char*)As1 + aoff;
  const char* rB1 = (const char*)Bs1 + boff;

  const f32x4 fzero = {0.f, 0.f, 0.f, 0.f};
  f32x4 acc[4][4];
#pragma unroll
  for (int m = 0; m < 4; ++m)
#pragma unroll
    for (int n = 0; n < 4; ++n) acc[m][n] = fzero;

  auto compute = [&](const char* rA, const char* rB) {
    short8x aF[4], bF[4];
#pragma unroll
    for (int m = 0; m < 4; ++m) aF[m] = *(const short8x*)(rA + m * 1024);
#pragma unroll
    for (int n = 0; n < 4; ++n) bF[n] = *(const short8x*)(rB + n * 1024);
#pragma unroll
    for (int m = 0; m < 4; ++m)
#pragma unroll
      for (int n = 0; n < 4; ++n)
        acc[m][n] = __builtin_amdgcn_mfma_f32_16x16x32_bf16(aF[m], bF[n], acc[m][n], 0, 0, 0);
  };

  gl_lds16(gA0, dA0); gl_lds16(gA1, dA0 + 4096);
  gl_lds16(gB0, dB0); gl_lds16(gB1, dB0 + 4096);
  gA0 += 64; gA1 += 64; gB0 += 64; gB1 += 64;
  __syncthreads();

  const int nk2 = Kit >> 6;
  for (int p = 0; p < nk2; ++p) {
    gl_lds16(gA0, dA1); gl_lds16(gA1, dA1 + 4096);
    gl_lds16(gB0, dB1); gl_lds16(gB1, dB1 + 4096);
    gA0 += 64; gA1 += 64; gB0 += 64; gB1 += 64;
    compute(rA0, rB0);
    __syncthreads();
    if (p + 1 < nk2) {
      gl_lds16(gA0, dA0); gl_lds16(gA1, dA0 + 4096);
      gl_lds16(gB0, dB0); gl_lds16(gB1, dB0 + 4096);
    }
    gA0 += 64; gA1 += 64; gB0 += 64; gB1 += 64;
    compute(rA1, rB1);
    __syncthreads();
  }

#pragma unroll
  for (int m = 0; m < 4; ++m) {
#pragma unroll
    for (int rr = 0; rr < 4; ++rr) {
      const int gm = m0 + wr + m * 16 + lkg * 4 + rr;
#pragma unroll
      for (int n = 0; n < 4; ++n) {
        const int gn = n0 + wc + n * 16 + lr;
        float v = acc[m][n][rr];
        if (EPI == 2) v += bias[gn];
        if (EPI == 2) v = 0.5f * v * (1.0f + erff(v * 0.70710678118654752f));
        if (EPI == 4) v *= 0.125f;
        if (EPI == 5 && gn < 1024) v *= 0.125f;
        if (EPI == 1)
          ((float*)C)[(size_t)blockIdx.z * zC + (size_t)gm * ldc + gn] = v;
        else
          ((u16*)C)[(size_t)blockIdx.z * zC + (size_t)gm * ldc + gn] = f2bf(v);
      }
    }
  }
}

// ---- merged Q2 (scale 1/8 -> QKV ldc 3072) + KV2 (plain -> KV2buf ldc 2048) ----
__global__ __launch_bounds__(256, 3) void gemm_q2kv2(const u16* __restrict__ A1, const u16* __restrict__ B1,
                                                     u16* __restrict__ C1, const u16* __restrict__ A2,
                                                     const u16* __restrict__ B2, u16* __restrict__ C2) {
  __shared__ u16 As0[128 * 32], Bs0[128 * 32];
  __shared__ u16 As1[128 * 32], Bs1[128 * 32];
  const int t = threadIdx.x;
  const int wave = t >> 6, lane = t & 63;
  const int lr = lane & 15, lkg = lane >> 4;
  const int swz = (lr >> 1) & 3;
  const int wr = (wave >> 1) * 64, wc = (wave & 1) * 64;

  const int nwg = 24 * 64;
  const int flat = blockIdx.y * 24 + blockIdx.x;
  const int wg = (flat & 7) * (nwg >> 3) + (flat >> 3);

  const int sub = (wg >= 512);
  const int wl = sub ? (wg - 512) : wg;
  const int gxl = sub ? 16 : 8;
  const int m0 = (wl / gxl) * 128, n0 = (wl % gxl) * 128;
  const u16* A = sub ? A2 : A1;
  const u16* Bt = sub ? B2 : B1;
  u16* C = sub ? C2 : C1;
  const int ldc = sub ? 2048 : 3072;
  const float scale = sub ? 1.0f : 0.125f;

  const int schunk = ((t & 3) ^ ((t >> 3) & 3)) << 4;
  const size_t rowb = 2048;
  const size_t rowskip = (size_t)64 * rowb;
  const char* gA0 = (const char*)A + (size_t)(m0 + (t >> 2)) * rowb + schunk;
  const char* gA1 = gA0 + rowskip;
  const char* gB0 = (const char*)Bt + (size_t)(n0 + (t >> 2)) * rowb + schunk;
  const char* gB1 = gB0 + rowskip;

  char* dA0 = (char*)As0 + wave * 1024;
  char* dB0 = (char*)Bs0 + wave * 1024;
  char* dA1 = (char*)As1 + wave * 1024;
  char* dB1 = (char*)Bs1 + wave * 1024;

  const int aoff = (wr + lr) * 64 + ((lkg ^ swz) << 4);
  const int boff = (wc + lr) * 64 + ((lkg ^ swz) << 4);
  const char* rA0 = (const char*)As0 + aoff;
  const char* rB0 = (const char*)Bs0 + boff;
  const char* rA1 = (const char*)As1 + aoff;
  const char* rB1 = (const char*)Bs1 + boff;

  const f32x4 fzero = {0.f, 0.f, 0.f, 0.f};
  f32x4 acc[4][4];
#pragma unroll
  for (int m = 0; m < 4; ++m)
#pragma unroll
    for (int n = 0; n < 4; ++n) acc[m][n] = fzero;

  auto compute = [&](const char* rA, const char* rB) {
    short8x aF[4], bF[4];
#pragma unroll
    for (int m = 0; m < 4; ++m) aF[m] = *(const short8x*)(rA + m * 1024);
#pragma unroll
    for (int n = 0; n < 4; ++n) bF[n] = *(const short8x*)(rB + n * 1024);
#pragma unroll
    for (int m = 0; m < 4; ++m)
#pragma unroll
      for (int n = 0; n < 4; ++n)
        acc[m][n] = __builtin_amdgcn_mfma_f32_16x16x32_bf16(aF[m], bF[n], acc[m][n], 0, 0, 0);
  };

  gl_lds16(gA0, dA0); gl_lds16(gA1, dA0 + 4096);
  gl_lds16(gB0, dB0); gl_lds16(gB1, dB0 + 4096);
  gA0 += 64; gA1 += 64; gB0 += 64; gB1 += 64;
  __syncthreads();

  for (int p = 0; p < 16; ++p) {
    gl_lds16(gA0, dA1); gl_lds16(gA1, dA1 + 4096);
    gl_lds16(gB0, dB1); gl_lds16(gB1, dB1 + 4096);
    gA0 += 64; gA1 += 64; gB0 += 64; gB1 += 64;
    compute(rA0, rB0);
    __syncthreads();
    if (p + 1 < 16) {
      gl_lds16(gA0, dA0); gl_lds16(gA1, dA0 + 4096);
      gl_lds16(gB0, dB0); gl_lds16(gB1, dB0 + 4096);
    }
    gA0 += 64; gA1 += 64; gB0 += 64; gB1 += 64;
    compute(rA1, rB1);
    __syncthreads();
  }

#pragma unroll
  for (int m = 0; m < 4; ++m) {
#pragma unroll
    for (int rr = 0; rr < 4; ++rr) {
      const int gm = m0 + wr + m * 16 + lkg * 4 + rr;
#pragma unroll
      for (int n = 0; n < 4; ++n) {
        const int gn = n0 + wc + n * 16 + lr;
        C[(size_t)gm * ldc + gn] = f2bf(acc[m][n][rr] * scale);
      }
    }
  }
}

// ---------------- flash attention (verified; separate Q/K strides, causal longest-first) ----------------
template <int CAUSAL>
__global__ __launch_bounds__(256, 2) void flash_attn(const u16* __restrict__ Q, const u16* __restrict__ Kk,
                                                     const u16* __restrict__ Vt, u16* __restrict__ O,
                                                     int qst, int kst) {
  __shared__ u16 Ks[2][64 * 64];
  __shared__ u16 Vs[2][64 * 64];
  __shared__ u16 Ps[4][32 * 72];
  const int t = threadIdx.x;
  const int wave = t >> 6, lane = t & 63;
  const int lr = lane & 15, lkg = lane >> 4, lk = lkg * 8;
  const int sw = lr & 7;
  const int bh = blockIdx.y;
  const u16* Qb = Q + (size_t)(bh >> 4) * (1024 * (size_t)qst) + (bh & 15) * 64;
  const u16* Kb = Kk + (size_t)(bh >> 4) * (1024 * (size_t)kst) + (bh & 15) * 64;
  const u16* Vtb = Vt + (size_t)bh * (64 * 1024);
  u16* Ob = O + (size_t)(bh >> 4) * (1024 * 1024) + (bh & 15) * 64;
  const int qt = (gridDim.x - 1 - blockIdx.x) * 128;
  const int qw = qt + wave * 32;

  const f32x4 fzero = {0.f, 0.f, 0.f, 0.f};
  short8x qf[2][2];
#pragma unroll
  for (int rb = 0; rb < 2; ++rb)
#pragma unroll
    for (int kk = 0; kk < 2; ++kk)
      qf[rb][kk] = *(const short8x*)(Qb + (size_t)(qw + rb * 16 + lr) * qst + kk * 32 + lk);

  float m_[2][4], l_[2][4];
  f32x4 o_[2][4];
#pragma unroll
  for (int rb = 0; rb < 2; ++rb) {
#pragma unroll
    for (int rr = 0; rr < 4; ++rr) { m_[rb][rr] = -1e30f; l_[rb][rr] = 0.f; }
#pragma unroll
    for (int db = 0; db < 4; ++db) o_[rb][db] = fzero;
  }

  const int rsel = lane >> 3;
  const int csw = ((lane & 7) ^ rsel) << 4;

  auto stage = [&](int buf, int kv0) {
#pragma unroll
    for (int s = 0; s < 2; ++s) {
      const int row = s * 32 + wave * 8 + rsel;
      gl_lds16((const char*)Kb + (size_t)(kv0 + row) * (size_t)(kst * 2) + csw,
               (char*)&Ks[buf][0] + s * 4096 + wave * 1024);
      gl_lds16((const char*)Vtb + (size_t)row * 2048 + (size_t)kv0 * 2 + csw,
               (char*)&Vs[buf][0] + s * 4096 + wave * 1024);
    }
  };

  const int kv_end = CAUSAL ? (qt + 128) : 1024;
  const int nt = kv_end >> 6;

  stage(0, 0);
  __syncthreads();
  int cur = 0;
  for (int tt = 0; tt < nt; ++tt) {
    const int kv0 = tt * 64;
    if (tt + 1 < nt) stage(cur ^ 1, kv0 + 64);

    const char* ksb = (const char*)&Ks[cur][0];
    const char* vsb = (const char*)&Vs[cur][0];

    short8x kf[4][2];
#pragma unroll
    for (int nb = 0; nb < 4; ++nb) {
      const int row = nb * 16 + lr;
#pragma unroll
      for (int kk = 0; kk < 2; ++kk)
        kf[nb][kk] = *(const short8x*)(ksb + row * 128 + (((kk * 4 + lkg) ^ sw) << 4));
    }

#pragma unroll
    for (int rb = 0; rb < 2; ++rb) {
      f32x4 s[4];
#pragma unroll
      for (int nb = 0; nb < 4; ++nb) {
        s[nb] = __builtin_amdgcn_mfma_f32_16x16x32_bf16(qf[rb][0], kf[nb][0], fzero, 0, 0, 0);
        s[nb] = __builtin_amdgcn_mfma_f32_16x16x32_bf16(qf[rb][1], kf[nb][1], s[nb], 0, 0, 0);
      }
      if (CAUSAL && (kv0 + 63 > qw + rb * 16)) {
#pragma unroll
        for (int rr = 0; rr < 4; ++rr) {
          const int qg = qw + rb * 16 + lkg * 4 + rr;
#pragma unroll
          for (int nb = 0; nb < 4; ++nb)
            if (kv0 + nb * 16 + lr > qg) s[nb][rr] = -1e30f;
        }
      }
#pragma unroll
      for (int rr = 0; rr < 4; ++rr) {
        float mx = fmaxf(fmaxf(s[0][rr], s[1][rr]), fmaxf(s[2][rr], s[3][rr]));
#pragma unroll
        for (int d = 1; d < 16; d <<= 1) mx = fmaxf(mx, __shfl_xor(mx, d, 16));
        const float mold = m_[rb][rr];
        const float mnew = fmaxf(mold, mx);
        float p[4];
#pragma unroll
        for (int nb = 0; nb < 4; ++nb) p[nb] = __expf(s[nb][rr] - mnew);
        float rsum = (p[0] + p[1]) + (p[2] + p[3]);
#pragma unroll
        for (int d = 1; d < 16; d <<= 1) rsum += __shfl_xor(rsum, d, 16);
        const float alpha = __expf(mold - mnew);
        m_[rb][rr] = mnew;
        l_[rb][rr] = l_[rb][rr] * alpha + rsum;
#pragma unroll
        for (int db = 0; db < 4; ++db) o_[rb][db][rr] *= alpha;
        const int prow = rb * 16 + lkg * 4 + rr;
#pragma unroll
        for (int nb = 0; nb < 4; ++nb)
          Ps[wave][prow * 72 + nb * 16 + lr] = f2bf(p[nb]);
      }
    }
    asm volatile("s_waitcnt lgkmcnt(0)" ::: "memory");

    short8x vF[4][2];
#pragma unroll
    for (int db = 0; db < 4; ++db) {
      const int row = db * 16 + lr;
#pragma unroll
      for (int kk = 0; kk < 2; ++kk)
        vF[db][kk] = *(const short8x*)(vsb + row * 128 + (((kk * 4 + lkg) ^ sw) << 4));
    }
#pragma unroll
    for (int rb = 0; rb < 2; ++rb) {
#pragma unroll
      for (int kk = 0; kk < 2; ++kk) {
        const short8x aP = *(const short8x*)((const char*)&Ps[wave][0] + (rb * 16 + lr) * 144 + kk * 64 + lkg * 16);
#pragma unroll
        for (int db = 0; db < 4; ++db)
          o_[rb][db] = __builtin_amdgcn_mfma_f32_16x16x32_bf16(aP, vF[db][kk], o_[rb][db], 0, 0, 0);
      }
    }
    __syncthreads();
    cur ^= 1;
  }

#pragma unroll
  for (int rb = 0; rb < 2; ++rb)
#pragma unroll
    for (int rr = 0; rr < 4; ++rr) {
      const float inv = 1.0f / l_[rb][rr];
      const int qg = qw + rb * 16 + lkg * 4 + rr;
#pragma unroll
      for (int db = 0; db < 4; ++db)
        Ob[(size_t)qg * 1024 + db * 16 + lr] = f2bf(o_[rb][db][rr] * inv);
    }
}

// ---------------- LayerNorm(X [+X2] [+bias] + R); XB=1: X/X2 are bf16 ----------------
template <int XB>
__global__ __launch_bounds__(256) void ln_res(const void* __restrict__ Xv, const void* __restrict__ X2v,
                                              const float* __restrict__ bias, const float* __restrict__ R,
                                              const float* __restrict__ gam, const float* __restrict__ bet,
                                              float* __restrict__ oF, u16* __restrict__ oB) {
  __shared__ float red[8];
  const int row = blockIdx.x, t = threadIdx.x;
  const int wave = t >> 6, lane = t & 63;
  const size_t off = (size_t)row * 1024 + t * 4;
  float v[4];
  if (XB) {
    u16x4 x = *(const u16x4*)((const u16*)Xv + off);
#pragma unroll
    for (int j = 0; j < 4; ++j) v[j] = bf2f(x[j]);
  } else {
    f4 x = *(const f4*)((const float*)Xv + off);
#pragma unroll
    for (int j = 0; j < 4; ++j) v[j] = x[j];
  }
  f4 r = *(const f4*)(R + off);
#pragma unroll
  for (int j = 0; j < 4; ++j) v[j] += r[j];
  if (X2v) {
    if (XB) {
      u16x4 x2 = *(const u16x4*)((const u16*)X2v + off);
#pragma unroll
      for (int j = 0; j < 4; ++j) v[j] += bf2f(x2[j]);
    } else {
      f4 x2 = *(const f4*)((const float*)X2v + off);
#pragma unroll
      for (int j = 0; j < 4; ++j) v[j] += x2[j];
    }
  }
  if (bias) {
    f4 bb = *(const f4*)(bias + t * 4);
#pragma unroll
    for (int j = 0; j < 4; ++j) v[j] += bb[j];
  }
  float s = 0.f, sq = 0.f;
#pragma unroll
  for (int j = 0; j < 4; ++j) { s += v[j]; sq += v[j] * v[j]; }
#pragma unroll
  for (int d = 1; d < 64; d <<= 1) {
    s += __shfl_xor(s, d, 64);
    sq += __shfl_xor(sq, d, 64);
  }
  if (lane == 0) { red[wave * 2] = s; red[wave * 2 + 1] = sq; }
  __syncthreads();
  s = red[0] + red[2] + red[4] + red[6];
  sq = red[1] + red[3] + red[5] + red[7];
  const float mu = s * (1.0f / 1024.0f);
  const float var = sq * (1.0f / 1024.0f) - mu * mu;
  const float rs = rsqrtf(var + 1e-5f);
  f4 g4 = *(const f4*)(gam + t * 4);
  f4 b4 = *(const f4*)(bet + t * 4);
  f4 y;
#pragma unroll
  for (int j = 0; j < 4; ++j) y[j] = (v[j] - mu) * rs * g4[j] + b4[j];
  *(f4*)(oF + off) = y;
  if (oB) {
    u16x4 yb;
#pragma unroll
    for (int j = 0; j < 4; ++j) yb[j] = f2bf(y[j]);
    *(u16x4*)(oB + off) = yb;
  }
}

// ---------------- launcher ----------------
extern "C" void kernel_launch(void* const* d_in, const int* in_sizes, int n_in,
                              void* d_out, int out_size, void* d_ws, size_t ws_size,
                              hipStream_t stream) {
  const float* embeds = (const float*)d_in[0];
  const float* enc = (const float*)d_in[1];
  const float* wq1 = (const float*)d_in[2];
  const float* wk1 = (const float*)d_in[3];
  const float* wv1 = (const float*)d_in[4];
  const float* wo1 = (const float*)d_in[5];
  const float* wq2 = (const float*)d_in[6];
  const float* wk2 = (const float*)d_in[7];
  const float* wv2 = (const float*)d_in[8];
  const float* wo2 = (const float*)d_in[9];
  const float* ln1g = (const float*)d_in[10];
  const float* ln1b = (const float*)d_in[11];
  const float* ln2g = (const float*)d_in[12];
  const float* ln2b = (const float*)d_in[13];
  const float* ln3g = (const float*)d_in[14];
  const float* ln3b = (const float*)d_in[15];
  const float* w1 = (const float*)d_in[16];
  const float* b1 = (const float*)d_in[17];
  const float* w2 = (const float*)d_in[18];
  const float* b2 = (const float*)d_in[19];
  float* out = (float*)d_out;
  char* ws = (char*)d_ws;
  const size_t MB = (size_t)1 << 20;

  u16* QKV = (u16*)(ws + 0 * MB);      // 48MB [8192, 3072] bf16 (layer1 QKV; layer2 Q cols 0..1023)
  u16* Vtb = (u16*)(ws + 48 * MB);     // 16MB
  u16* Hd = (u16*)(ws + 64 * MB);      // 16MB heads
  u16* Ob16 = (u16*)(ws + 80 * MB);    // 16MB bf16 gemm out (Wo / FF2 z0)
  u16* Ob16b = (u16*)(ws + 96 * MB);   // 16MB (FF2 z1 partial)
  u16* ebf = (u16*)(ws + 112 * MB);    // 16MB (x1 bf16 later; dead by FF2)
  u16* encb = (u16*)(ws + 128 * MB);   // 16MB (x2 bf16 later)
  float* x1f = (float*)(ws + 144 * MB);
  float* x2f = (float*)(ws + 176 * MB);  // KV2 also lives here pre-LN2
  u16* Wq1t = (u16*)(ws + 208 * MB);   // z0..z2: Wq1/Wk1/Wv1 (fused QKV1)
  u16* Wq2t = (u16*)(ws + 214 * MB);   // z3
  u16* Wk2t = (u16*)(ws + 216 * MB);   // z4,z5: Wk2/Wv2 (fused KV2)
  u16* Wo1b = (u16*)(ws + 220 * MB);
  u16* Wo2b = (u16*)(ws + 222 * MB);
  u16* W1b = (u16*)(ws + 224 * MB);  // 8MB
  u16* W2b = (u16*)(ws + 232 * MB);  // 8MB, end = 240MB
  u16* x1b = ebf;
  u16* x2b = encb;
  u16* Hff = (u16*)(ws + 0 * MB);  // 64MB, reuses QKV/Vtb after attn2

  u16* KV2 = (u16*)(ws + 176 * MB);  // 32MB [8192, 2048] bf16, layer-2 K|V
  const long long ZC16 = (long long)8192 * 1024;  // 16MB in u16 elems

  dim3 blk(256);

  cast_bf16_2<<<dim3(8192, 2), blk, 0, stream>>>(embeds, enc, ebf, encb);
  cast_wqkv6<<<dim3(16, 16, 6), blk, 0, stream>>>(wq1, wk1, wv1, wq2, wk2, wv2, Wq1t);
  cast_bf16_2<<<dim3(1024, 2), blk, 0, stream>>>(wo1, wo2, Wo1b, Wo2b);
  cast_bf16_2<<<dim3(4096, 2), blk, 0, stream>>>(w1, w2, W1b, W2b);

  // ---- masked self-attention + LN1 ----
  gemm_bt<5><<<dim3(24, 64), blk, 0, stream>>>(ebf, Wq1t, QKV, nullptr, 1024, 1024, 3072, 0);
  transpose_v<<<dim3(32, 128), blk, 0, stream>>>(QKV, Vtb, 3072, 2048);
  flash_attn<1><<<dim3(8, 128), blk, 0, stream>>>(QKV, QKV + 1024, Vtb, Hd, 3072, 3072);
  gemm_bt<0><<<dim3(8, 64), blk, 0, stream>>>(Hd, Wo1b, Ob16, nullptr, 1024, 1024, 1024, 0);
  ln_res<1><<<8192, blk, 0, stream>>>(Ob16, nullptr, nullptr, embeds, ln1g, ln1b, x1f, x1b);

  // ---- cross-attention + LN2 ----
  gemm_q2kv2<<<dim3(24, 64), blk, 0, stream>>>(x1b, Wq2t, QKV, encb, Wk2t, KV2);
  transpose_v<<<dim3(32, 128), blk, 0, stream>>>(KV2, Vtb, 2048, 1024);
  flash_attn<0><<<dim3(8, 128), blk, 0, stream>>>(QKV, KV2, Vtb, Hd, 3072, 2048);
  gemm_bt<0><<<dim3(8, 64), blk, 0, stream>>>(Hd, Wo2b, Ob16, nullptr, 1024, 1024, 1024, 0);
  ln_res<1><<<8192, blk, 0, stream>>>(Ob16, nullptr, nullptr, x1f, ln2g, ln2b, x2f, x2b);

  // ---- feed-forward + LN3 ----
  gemm_bt<2><<<dim3(32, 64), blk, 0, stream>>>(x2b, W1b, Hff, b1, 1024, 1024, 4096, 0);
  // FF2 split-K z=2 -> bf16 partials (z0 -> Ob16, z1 -> Ob16b); bias b2 merged in LN3
  gemm_bt<0><<<dim3(8, 64, 2), blk, 0, stream>>>(Hff, W2b, Ob16, nullptr, 4096, 2048, 1024, ZC16);
  ln_res<1><<<8192, blk, 0, stream>>>(Ob16, Ob16b, b2, x2f, ln3g, ln3b, out, nullptr);
}

// Round 17
// 668.231 us; speedup vs baseline: 1.0704x; 1.0290x over previous
//
#include <hip/hip_runtime.h>
#include <cstdint>
#include <cstddef>

typedef unsigned short u16;
typedef __attribute__((ext_vector_type(4))) float f32x4;
typedef __attribute__((ext_vector_type(4))) float f4;
typedef __attribute__((ext_vector_type(8))) short short8x;
typedef __attribute__((ext_vector_type(4))) u16 u16x4;
typedef __attribute__((ext_vector_type(8))) u16 u16x8;

#define DEV static __device__ __forceinline__

DEV void gl_lds16(const void* g, void* l) {
  __builtin_amdgcn_global_load_lds(
      (const __attribute__((address_space(1))) unsigned int*)g,
      (__attribute__((address_space(3))) unsigned int*)l, 16, 0, 0);
}

DEV u16 f2bf(float f) {
  unsigned u = __float_as_uint(f);
  u += 0x7fffu + ((u >> 16) & 1u);
  return (u16)(u >> 16);
}
DEV float bf2f(u16 b) { return __uint_as_float(((unsigned)b) << 16); }

// ---------------- cast / pack kernels ----------------

__global__ __launch_bounds__(256) void cast_bf16_2(const float* __restrict__ X0, const float* __restrict__ X1,
                                                   u16* __restrict__ Y0, u16* __restrict__ Y1) {
  const float* X = blockIdx.y ? X1 : X0;
  u16* Y = blockIdx.y ? Y1 : Y0;
  size_t i = ((size_t)blockIdx.x * 256 + threadIdx.x) * 4;
  f4 v = *(const f4*)(X + i);
  u16x4 y;
#pragma unroll
  for (int j = 0; j < 4; ++j) y[j] = f2bf(v[j]);
  *(u16x4*)(Y + i) = y;
}

// 6x wq [H,D,DH] f32 -> Wt [H*DH, D] bf16 (B^T form), dsts contiguous at Wbase + z*1M elems
__global__ __launch_bounds__(256) void cast_wqkv6(const float* __restrict__ W0, const float* __restrict__ W1,
                                                  const float* __restrict__ W2, const float* __restrict__ W3,
                                                  const float* __restrict__ W4, const float* __restrict__ W5,
                                                  u16* __restrict__ Wbase) {
  __shared__ float tile[64][65];
  const int t = threadIdx.x;
  const int h = blockIdx.y;
  const int z = blockIdx.z;
  const int d0 = blockIdx.x * 64;
  const float* W = (z == 0) ? W0 : (z == 1) ? W1 : (z == 2) ? W2 : (z == 3) ? W3 : (z == 4) ? W4 : W5;
  u16* Wt = Wbase + (size_t)z * (1024 * 1024);
  const float* Wb = W + (size_t)h * (1024 * 64);
  const int di = t >> 2;
  const int j0 = (t & 3) * 16;
#pragma unroll
  for (int c = 0; c < 4; ++c) {
    f4 v = *(const f4*)(Wb + (size_t)(d0 + di) * 64 + j0 + c * 4);
#pragma unroll
    for (int j = 0; j < 4; ++j) tile[di][j0 + c * 4 + j] = v[j];
  }
  __syncthreads();
  const int k = t >> 2;
  const int dd0 = (t & 3) * 16;
  u16x8 o0, o1;
#pragma unroll
  for (int u = 0; u < 8; ++u) o0[u] = f2bf(tile[dd0 + u][k]);
#pragma unroll
  for (int u = 0; u < 8; ++u) o1[u] = f2bf(tile[dd0 + 8 + u][k]);
  u16* dst = Wt + (size_t)(h * 64 + k) * 1024 + d0 + dd0;
  *(u16x8*)(dst) = o0;
  *(u16x8*)(dst + 8) = o1;
}

// V columns of src [B,S,vstride] bf16 -> Vt [B*H, DH, S] bf16
__global__ __launch_bounds__(256) void transpose_v(const u16* __restrict__ V, u16* __restrict__ Vt,
                                                   int vstride, int voff) {
  __shared__ u16 tile[32][72];
  const int t = threadIdx.x;
  const int bh = blockIdx.y;
  const int s0 = blockIdx.x * 32;
  const u16* Vb = V + (size_t)(bh >> 4) * (1024 * (size_t)vstride) + voff + (bh & 15) * 64;
  const int si = t >> 3, d0 = (t & 7) * 8;
  u16x8 val = *(const u16x8*)(Vb + (size_t)(s0 + si) * vstride + d0);
#pragma unroll
  for (int u = 0; u < 8; ++u) tile[si][d0 + u] = val[u];
  __syncthreads();
  const int d = t >> 2, sj0 = (t & 3) * 8;
  u16x8 o;
#pragma unroll
  for (int u = 0; u < 8; ++u) o[u] = tile[sj0 + u][d];
  *(u16x8*)(Vt + (size_t)bh * (64 * 1024) + (size_t)d * 1024 + s0 + sj0) = o;
}

// ---------------- GEMM 128x128, BK=32, 2-phase, static ping-pong (R7-verified) ----------------
// EPI: 0=bf16 (+zC elem offset for split-K), 1=f32 (+zC), 2=bias+GELU->bf16,
//      4=scale(1/8)->bf16, 5=QKV scale cols<1024
template <int EPI>
__global__ __launch_bounds__(256, 3) void gemm_bt(const u16* __restrict__ A, const u16* __restrict__ Bt,
                                                  void* __restrict__ C, const float* __restrict__ bias,
                                                  int Krow, int Kit, int ldc, long long zC) {
  __shared__ u16 As0[128 * 32], Bs0[128 * 32];
  __shared__ u16 As1[128 * 32], Bs1[128 * 32];
  const int t = threadIdx.x;
  const int wave = t >> 6, lane = t & 63;
  const int lr = lane & 15, lkg = lane >> 4;
  const int swz = (lr >> 1) & 3;
  const int wr = (wave >> 1) * 64, wc = (wave & 1) * 64;

  const int gx = gridDim.x;
  const int nwg = gx * gridDim.y;
  const int flat = blockIdx.y * gx + blockIdx.x;
  const int wg = (flat & 7) * (nwg >> 3) + (flat >> 3);
  const int m0 = (wg / gx) * 128, n0 = (wg % gx) * 128;

  const int schunk = ((t & 3) ^ ((t >> 3) & 3)) << 4;
  const size_t rowb = (size_t)Krow * 2;
  const size_t rowskip = (size_t)64 * rowb;
  const size_t zoff = (size_t)blockIdx.z * (size_t)Kit * 2;
  const char* gA0 = (const char*)A + (size_t)(m0 + (t >> 2)) * rowb + zoff + schunk;
  const char* gA1 = gA0 + rowskip;
  const char* gB0 = (const char*)Bt + (size_t)(n0 + (t >> 2)) * rowb + zoff + schunk;
  const char* gB1 = gB0 + rowskip;

  char* dA0 = (char*)As0 + wave * 1024;
  char* dB0 = (char*)Bs0 + wave * 1024;
  char* dA1 = (char*)As1 + wave * 1024;
  char* dB1 = (char*)Bs1 + wave * 1024;

  const int aoff = (wr + lr) * 64 + ((lkg ^ swz) << 4);
  const int boff = (wc + lr) * 64 + ((lkg ^ swz) << 4);
  const char* rA0 = (const char*)As0 + aoff;
  const char* rB0 = (const char*)Bs0 + boff;
  const char* rA1 = (const char*)As1 + aoff;
  const char* rB1 = (const char*)Bs1 + boff;

  const f32x4 fzero = {0.f, 0.f, 0.f, 0.f};
  f32x4 acc[4][4];
#pragma unroll
  for (int m = 0; m < 4; ++m)
#pragma unroll
    for (int n = 0; n < 4; ++n) acc[m][n] = fzero;

  auto compute = [&](const char* rA, const char* rB) {
    short8x aF[4], bF[4];
#pragma unroll
    for (int m = 0; m < 4; ++m) aF[m] = *(const short8x*)(rA + m * 1024);
#pragma unroll
    for (int n = 0; n < 4; ++n) bF[n] = *(const short8x*)(rB + n * 1024);
#pragma unroll
    for (int m = 0; m < 4; ++m)
#pragma unroll
      for (int n = 0; n < 4; ++n)
        acc[m][n] = __builtin_amdgcn_mfma_f32_16x16x32_bf16(aF[m], bF[n], acc[m][n], 0, 0, 0);
  };

  gl_lds16(gA0, dA0); gl_lds16(gA1, dA0 + 4096);
  gl_lds16(gB0, dB0); gl_lds16(gB1, dB0 + 4096);
  gA0 += 64; gA1 += 64; gB0 += 64; gB1 += 64;
  __syncthreads();

  const int nk2 = Kit >> 6;
  for (int p = 0; p < nk2; ++p) {
    gl_lds16(gA0, dA1); gl_lds16(gA1, dA1 + 4096);
    gl_lds16(gB0, dB1); gl_lds16(gB1, dB1 + 4096);
    gA0 += 64; gA1 += 64; gB0 += 64; gB1 += 64;
    compute(rA0, rB0);
    __syncthreads();
    if (p + 1 < nk2) {
      gl_lds16(gA0, dA0); gl_lds16(gA1, dA0 + 4096);
      gl_lds16(gB0, dB0); gl_lds16(gB1, dB0 + 4096);
    }
    gA0 += 64; gA1 += 64; gB0 += 64; gB1 += 64;
    compute(rA1, rB1);
    __syncthreads();
  }

#pragma unroll
  for (int m = 0; m < 4; ++m) {
#pragma unroll
    for (int rr = 0; rr < 4; ++rr) {
      const int gm = m0 + wr + m * 16 + lkg * 4 + rr;
#pragma unroll
      for (int n = 0; n < 4; ++n) {
        const int gn = n0 + wc + n * 16 + lr;
        float v = acc[m][n][rr];
        if (EPI == 2) v += bias[gn];
        if (EPI == 2) v = 0.5f * v * (1.0f + erff(v * 0.70710678118654752f));
        if (EPI == 4) v *= 0.125f;
        if (EPI == 5 && gn < 1024) v *= 0.125f;
        if (EPI == 1)
          ((float*)C)[(size_t)blockIdx.z * zC + (size_t)gm * ldc + gn] = v;
        else
          ((u16*)C)[(size_t)blockIdx.z * zC + (size_t)gm * ldc + gn] = f2bf(v);
      }
    }
  }
}

// ---- merged Q2 (scale 1/8 -> QKV ldc 3072) + KV2 (plain -> KV2buf ldc 2048) ----
__global__ __launch_bounds__(256, 3) void gemm_q2kv2(const u16* __restrict__ A1, const u16* __restrict__ B1,
                                                     u16* __restrict__ C1, const u16* __restrict__ A2,
                                                     const u16* __restrict__ B2, u16* __restrict__ C2) {
  __shared__ u16 As0[128 * 32], Bs0[128 * 32];
  __shared__ u16 As1[128 * 32], Bs1[128 * 32];
  const int t = threadIdx.x;
  const int wave = t >> 6, lane = t & 63;
  const int lr = lane & 15, lkg = lane >> 4;
  const int swz = (lr >> 1) & 3;
  const int wr = (wave >> 1) * 64, wc = (wave & 1) * 64;

  const int nwg = 24 * 64;
  const int flat = blockIdx.y * 24 + blockIdx.x;
  const int wg = (flat & 7) * (nwg >> 3) + (flat >> 3);

  const int sub = (wg >= 512);
  const int wl = sub ? (wg - 512) : wg;
  const int gxl = sub ? 16 : 8;
  const int m0 = (wl / gxl) * 128, n0 = (wl % gxl) * 128;
  const u16* A = sub ? A2 : A1;
  const u16* Bt = sub ? B2 : B1;
  u16* C = sub ? C2 : C1;
  const int ldc = sub ? 2048 : 3072;
  const float scale = sub ? 1.0f : 0.125f;

  const int schunk = ((t & 3) ^ ((t >> 3) & 3)) << 4;
  const size_t rowb = 2048;
  const size_t rowskip = (size_t)64 * rowb;
  const char* gA0 = (const char*)A + (size_t)(m0 + (t >> 2)) * rowb + schunk;
  const char* gA1 = gA0 + rowskip;
  const char* gB0 = (const char*)Bt + (size_t)(n0 + (t >> 2)) * rowb + schunk;
  const char* gB1 = gB0 + rowskip;

  char* dA0 = (char*)As0 + wave * 1024;
  char* dB0 = (char*)Bs0 + wave * 1024;
  char* dA1 = (char*)As1 + wave * 1024;
  char* dB1 = (char*)Bs1 + wave * 1024;

  const int aoff = (wr + lr) * 64 + ((lkg ^ swz) << 4);
  const int boff = (wc + lr) * 64 + ((lkg ^ swz) << 4);
  const char* rA0 = (const char*)As0 + aoff;
  const char* rB0 = (const char*)Bs0 + boff;
  const char* rA1 = (const char*)As1 + aoff;
  const char* rB1 = (const char*)Bs1 + boff;

  const f32x4 fzero = {0.f, 0.f, 0.f, 0.f};
  f32x4 acc[4][4];
#pragma unroll
  for (int m = 0; m < 4; ++m)
#pragma unroll
    for (int n = 0; n < 4; ++n) acc[m][n] = fzero;

  auto compute = [&](const char* rA, const char* rB) {
    short8x aF[4], bF[4];
#pragma unroll
    for (int m = 0; m < 4; ++m) aF[m] = *(const short8x*)(rA + m * 1024);
#pragma unroll
    for (int n = 0; n < 4; ++n) bF[n] = *(const short8x*)(rB + n * 1024);
#pragma unroll
    for (int m = 0; m < 4; ++m)
#pragma unroll
      for (int n = 0; n < 4; ++n)
        acc[m][n] = __builtin_amdgcn_mfma_f32_16x16x32_bf16(aF[m], bF[n], acc[m][n], 0, 0, 0);
  };

  gl_lds16(gA0, dA0); gl_lds16(gA1, dA0 + 4096);
  gl_lds16(gB0, dB0); gl_lds16(gB1, dB0 + 4096);
  gA0 += 64; gA1 += 64; gB0 += 64; gB1 += 64;
  __syncthreads();

  for (int p = 0; p < 16; ++p) {
    gl_lds16(gA0, dA1); gl_lds16(gA1, dA1 + 4096);
    gl_lds16(gB0, dB1); gl_lds16(gB1, dB1 + 4096);
    gA0 += 64; gA1 += 64; gB0 += 64; gB1 += 64;
    compute(rA0, rB0);
    __syncthreads();
    if (p + 1 < 16) {
      gl_lds16(gA0, dA0); gl_lds16(gA1, dA0 + 4096);
      gl_lds16(gB0, dB0); gl_lds16(gB1, dB0 + 4096);
    }
    gA0 += 64; gA1 += 64; gB0 += 64; gB1 += 64;
    compute(rA1, rB1);
    __syncthreads();
  }

#pragma unroll
  for (int m = 0; m < 4; ++m) {
#pragma unroll
    for (int rr = 0; rr < 4; ++rr) {
      const int gm = m0 + wr + m * 16 + lkg * 4 + rr;
#pragma unroll
      for (int n = 0; n < 4; ++n) {
        const int gn = n0 + wc + n * 16 + lr;
        C[(size_t)gm * ldc + gn] = f2bf(acc[m][n][rr] * scale);
      }
    }
  }
}

// ---------------- flash attention (verified; separate Q/K strides, causal longest-first) ----------------
template <int CAUSAL>
__global__ __launch_bounds__(256, 2) void flash_attn(const u16* __restrict__ Q, const u16* __restrict__ Kk,
                                                     const u16* __restrict__ Vt, u16* __restrict__ O,
                                                     int qst, int kst) {
  __shared__ u16 Ks[2][64 * 64];
  __shared__ u16 Vs[2][64 * 64];
  __shared__ u16 Ps[4][32 * 72];
  const int t = threadIdx.x;
  const int wave = t >> 6, lane = t & 63;
  const int lr = lane & 15, lkg = lane >> 4, lk = lkg * 8;
  const int sw = lr & 7;
  const int bh = blockIdx.y;
  const u16* Qb = Q + (size_t)(bh >> 4) * (1024 * (size_t)qst) + (bh & 15) * 64;
  const u16* Kb = Kk + (size_t)(bh >> 4) * (1024 * (size_t)kst) + (bh & 15) * 64;
  const u16* Vtb = Vt + (size_t)bh * (64 * 1024);
  u16* Ob = O + (size_t)(bh >> 4) * (1024 * 1024) + (bh & 15) * 64;
  const int qt = (gridDim.x - 1 - blockIdx.x) * 128;
  const int qw = qt + wave * 32;

  const f32x4 fzero = {0.f, 0.f, 0.f, 0.f};
  short8x qf[2][2];
#pragma unroll
  for (int rb = 0; rb < 2; ++rb)
#pragma unroll
    for (int kk = 0; kk < 2; ++kk)
      qf[rb][kk] = *(const short8x*)(Qb + (size_t)(qw + rb * 16 + lr) * qst + kk * 32 + lk);

  float m_[2][4], l_[2][4];
  f32x4 o_[2][4];
#pragma unroll
  for (int rb = 0; rb < 2; ++rb) {
#pragma unroll
    for (int rr = 0; rr < 4; ++rr) { m_[rb][rr] = -1e30f; l_[rb][rr] = 0.f; }
#pragma unroll
    for (int db = 0; db < 4; ++db) o_[rb][db] = fzero;
  }

  const int rsel = lane >> 3;
  const int csw = ((lane & 7) ^ rsel) << 4;

  auto stage = [&](int buf, int kv0) {
#pragma unroll
    for (int s = 0; s < 2; ++s) {
      const int row = s * 32 + wave * 8 + rsel;
      gl_lds16((const char*)Kb + (size_t)(kv0 + row) * (size_t)(kst * 2) + csw,
               (char*)&Ks[buf][0] + s * 4096 + wave * 1024);
      gl_lds16((const char*)Vtb + (size_t)row * 2048 + (size_t)kv0 * 2 + csw,
               (char*)&Vs[buf][0] + s * 4096 + wave * 1024);
    }
  };

  const int kv_end = CAUSAL ? (qt + 128) : 1024;
  const int nt = kv_end >> 6;

  stage(0, 0);
  __syncthreads();
  int cur = 0;
  for (int tt = 0; tt < nt; ++tt) {
    const int kv0 = tt * 64;
    if (tt + 1 < nt) stage(cur ^ 1, kv0 + 64);

    const char* ksb = (const char*)&Ks[cur][0];
    const char* vsb = (const char*)&Vs[cur][0];

    short8x kf[4][2];
#pragma unroll
    for (int nb = 0; nb < 4; ++nb) {
      const int row = nb * 16 + lr;
#pragma unroll
      for (int kk = 0; kk < 2; ++kk)
        kf[nb][kk] = *(const short8x*)(ksb + row * 128 + (((kk * 4 + lkg) ^ sw) << 4));
    }

#pragma unroll
    for (int rb = 0; rb < 2; ++rb) {
      f32x4 s[4];
#pragma unroll
      for (int nb = 0; nb < 4; ++nb) {
        s[nb] = __builtin_amdgcn_mfma_f32_16x16x32_bf16(qf[rb][0], kf[nb][0], fzero, 0, 0, 0);
        s[nb] = __builtin_amdgcn_mfma_f32_16x16x32_bf16(qf[rb][1], kf[nb][1], s[nb], 0, 0, 0);
      }
      if (CAUSAL && (kv0 + 63 > qw + rb * 16)) {
#pragma unroll
        for (int rr = 0; rr < 4; ++rr) {
          const int qg = qw + rb * 16 + lkg * 4 + rr;
#pragma unroll
          for (int nb = 0; nb < 4; ++nb)
            if (kv0 + nb * 16 + lr > qg) s[nb][rr] = -1e30f;
        }
      }
#pragma unroll
      for (int rr = 0; rr < 4; ++rr) {
        float mx = fmaxf(fmaxf(s[0][rr], s[1][rr]), fmaxf(s[2][rr], s[3][rr]));
#pragma unroll
        for (int d = 1; d < 16; d <<= 1) mx = fmaxf(mx, __shfl_xor(mx, d, 16));
        const float mold = m_[rb][rr];
        const float mnew = fmaxf(mold, mx);
        float p[4];
#pragma unroll
        for (int nb = 0; nb < 4; ++nb) p[nb] = __expf(s[nb][rr] - mnew);
        float rsum = (p[0] + p[1]) + (p[2] + p[3]);
#pragma unroll
        for (int d = 1; d < 16; d <<= 1) rsum += __shfl_xor(rsum, d, 16);
        const float alpha = __expf(mold - mnew);
        m_[rb][rr] = mnew;
        l_[rb][rr] = l_[rb][rr] * alpha + rsum;
#pragma unroll
        for (int db = 0; db < 4; ++db) o_[rb][db][rr] *= alpha;
        const int prow = rb * 16 + lkg * 4 + rr;
#pragma unroll
        for (int nb = 0; nb < 4; ++nb)
          Ps[wave][prow * 72 + nb * 16 + lr] = f2bf(p[nb]);
      }
    }
    asm volatile("s_waitcnt lgkmcnt(0)" ::: "memory");

    short8x vF[4][2];
#pragma unroll
    for (int db = 0; db < 4; ++db) {
      const int row = db * 16 + lr;
#pragma unroll
      for (int kk = 0; kk < 2; ++kk)
        vF[db][kk] = *(const short8x*)(vsb + row * 128 + (((kk * 4 + lkg) ^ sw) << 4));
    }
#pragma unroll
    for (int rb = 0; rb < 2; ++rb) {
#pragma unroll
      for (int kk = 0; kk < 2; ++kk) {
        const short8x aP = *(const short8x*)((const char*)&Ps[wave][0] + (rb * 16 + lr) * 144 + kk * 64 + lkg * 16);
#pragma unroll
        for (int db = 0; db < 4; ++db)
          o_[rb][db] = __builtin_amdgcn_mfma_f32_16x16x32_bf16(aP, vF[db][kk], o_[rb][db], 0, 0, 0);
      }
    }
    __syncthreads();
    cur ^= 1;
  }

#pragma unroll
  for (int rb = 0; rb < 2; ++rb)
#pragma unroll
    for (int rr = 0; rr < 4; ++rr) {
      const float inv = 1.0f / l_[rb][rr];
      const int qg = qw + rb * 16 + lkg * 4 + rr;
#pragma unroll
      for (int db = 0; db < 4; ++db)
        Ob[(size_t)qg * 1024 + db * 16 + lr] = f2bf(o_[rb][db][rr] * inv);
    }
}

// -------- LayerNorm(X [+X2] [+bias] + R); XB: X/X2 bf16; RB: R bf16; oF nullable --------
template <int XB, int RB>
__global__ __launch_bounds__(256) void ln_res(const void* __restrict__ Xv, const void* __restrict__ X2v,
                                              const float* __restrict__ bias, const void* __restrict__ Rv,
                                              const float* __restrict__ gam, const float* __restrict__ bet,
                                              float* __restrict__ oF, u16* __restrict__ oB) {
  __shared__ float red[8];
  const int row = blockIdx.x, t = threadIdx.x;
  const int wave = t >> 6, lane = t & 63;
  const size_t off = (size_t)row * 1024 + t * 4;
  float v[4];
  if (XB) {
    u16x4 x = *(const u16x4*)((const u16*)Xv + off);
#pragma unroll
    for (int j = 0; j < 4; ++j) v[j] = bf2f(x[j]);
  } else {
    f4 x = *(const f4*)((const float*)Xv + off);
#pragma unroll
    for (int j = 0; j < 4; ++j) v[j] = x[j];
  }
  if (RB) {
    u16x4 r = *(const u16x4*)((const u16*)Rv + off);
#pragma unroll
    for (int j = 0; j < 4; ++j) v[j] += bf2f(r[j]);
  } else {
    f4 r = *(const f4*)((const float*)Rv + off);
#pragma unroll
    for (int j = 0; j < 4; ++j) v[j] += r[j];
  }
  if (X2v) {
    if (XB) {
      u16x4 x2 = *(const u16x4*)((const u16*)X2v + off);
#pragma unroll
      for (int j = 0; j < 4; ++j) v[j] += bf2f(x2[j]);
    } else {
      f4 x2 = *(const f4*)((const float*)X2v + off);
#pragma unroll
      for (int j = 0; j < 4; ++j) v[j] += x2[j];
    }
  }
  if (bias) {
    f4 bb = *(const f4*)(bias + t * 4);
#pragma unroll
    for (int j = 0; j < 4; ++j) v[j] += bb[j];
  }
  float s = 0.f, sq = 0.f;
#pragma unroll
  for (int j = 0; j < 4; ++j) { s += v[j]; sq += v[j] * v[j]; }
#pragma unroll
  for (int d = 1; d < 64; d <<= 1) {
    s += __shfl_xor(s, d, 64);
    sq += __shfl_xor(sq, d, 64);
  }
  if (lane == 0) { red[wave * 2] = s; red[wave * 2 + 1] = sq; }
  __syncthreads();
  s = red[0] + red[2] + red[4] + red[6];
  sq = red[1] + red[3] + red[5] + red[7];
  const float mu = s * (1.0f / 1024.0f);
  const float var = sq * (1.0f / 1024.0f) - mu * mu;
  const float rs = rsqrtf(var + 1e-5f);
  f4 g4 = *(const f4*)(gam + t * 4);
  f4 b4 = *(const f4*)(bet + t * 4);
  f4 y;
#pragma unroll
  for (int j = 0; j < 4; ++j) y[j] = (v[j] - mu) * rs * g4[j] + b4[j];
  if (oF) *(f4*)(oF + off) = y;
  if (oB) {
    u16x4 yb;
#pragma unroll
    for (int j = 0; j < 4; ++j) yb[j] = f2bf(y[j]);
    *(u16x4*)(oB + off) = yb;
  }
}

// ---------------- launcher ----------------
extern "C" void kernel_launch(void* const* d_in, const int* in_sizes, int n_in,
                              void* d_out, int out_size, void* d_ws, size_t ws_size,
                              hipStream_t stream) {
  const float* embeds = (const float*)d_in[0];
  const float* enc = (const float*)d_in[1];
  const float* wq1 = (const float*)d_in[2];
  const float* wk1 = (const float*)d_in[3];
  const float* wv1 = (const float*)d_in[4];
  const float* wo1 = (const float*)d_in[5];
  const float* wq2 = (const float*)d_in[6];
  const float* wk2 = (const float*)d_in[7];
  const float* wv2 = (const float*)d_in[8];
  const float* wo2 = (const float*)d_in[9];
  const float* ln1g = (const float*)d_in[10];
  const float* ln1b = (const float*)d_in[11];
  const float* ln2g = (const float*)d_in[12];
  const float* ln2b = (const float*)d_in[13];
  const float* ln3g = (const float*)d_in[14];
  const float* ln3b = (const float*)d_in[15];
  const float* w1 = (const float*)d_in[16];
  const float* b1 = (const float*)d_in[17];
  const float* w2 = (const float*)d_in[18];
  const float* b2 = (const float*)d_in[19];
  float* out = (float*)d_out;
  char* ws = (char*)d_ws;
  const size_t MB = (size_t)1 << 20;

  u16* QKV = (u16*)(ws + 0 * MB);      // 48MB [8192, 3072] bf16 (layer1 QKV; layer2 Q cols 0..1023)
  u16* Vtb = (u16*)(ws + 48 * MB);     // 16MB
  u16* Hd = (u16*)(ws + 64 * MB);      // 16MB heads
  u16* Ob16 = (u16*)(ws + 80 * MB);    // 16MB bf16 gemm out (Wo / FF2 z0)
  u16* Ob16b = (u16*)(ws + 96 * MB);   // 16MB (FF2 z1 partial)
  u16* ebf = (u16*)(ws + 112 * MB);    // 16MB (x1 bf16 later; dead by FF2)
  u16* encb = (u16*)(ws + 128 * MB);   // 16MB (x2 bf16 later)
  u16* Wq1t = (u16*)(ws + 208 * MB);   // z0..z2: Wq1/Wk1/Wv1 (fused QKV1)
  u16* Wq2t = (u16*)(ws + 214 * MB);   // z3
  u16* Wk2t = (u16*)(ws + 216 * MB);   // z4,z5: Wk2/Wv2 (fused KV2)
  u16* Wo1b = (u16*)(ws + 220 * MB);
  u16* Wo2b = (u16*)(ws + 222 * MB);
  u16* W1b = (u16*)(ws + 224 * MB);  // 8MB
  u16* W2b = (u16*)(ws + 232 * MB);  // 8MB, end = 240MB
  u16* x1b = ebf;
  u16* x2b = encb;
  u16* Hff = (u16*)(ws + 0 * MB);  // 64MB, reuses QKV/Vtb after attn2

  u16* KV2 = (u16*)(ws + 176 * MB);  // 32MB [8192, 2048] bf16, layer-2 K|V
  const long long ZC16 = (long long)8192 * 1024;  // 16M u16 elems

  dim3 blk(256);

  cast_bf16_2<<<dim3(8192, 2), blk, 0, stream>>>(embeds, enc, ebf, encb);
  cast_wqkv6<<<dim3(16, 16, 6), blk, 0, stream>>>(wq1, wk1, wv1, wq2, wk2, wv2, Wq1t);
  cast_bf16_2<<<dim3(1024, 2), blk, 0, stream>>>(wo1, wo2, Wo1b, Wo2b);
  cast_bf16_2<<<dim3(4096, 2), blk, 0, stream>>>(w1, w2, W1b, W2b);

  // ---- masked self-attention + LN1 ----
  gemm_bt<5><<<dim3(24, 64), blk, 0, stream>>>(ebf, Wq1t, QKV, nullptr, 1024, 1024, 3072, 0);
  transpose_v<<<dim3(32, 128), blk, 0, stream>>>(QKV, Vtb, 3072, 2048);
  flash_attn<1><<<dim3(8, 128), blk, 0, stream>>>(QKV, QKV + 1024, Vtb, Hd, 3072, 3072);
  gemm_bt<0><<<dim3(8, 64), blk, 0, stream>>>(Hd, Wo1b, Ob16, nullptr, 1024, 1024, 1024, 0);
  // x1 kept only as bf16 (x1b); residual chain reads bf16 downstream
  ln_res<1, 0><<<8192, blk, 0, stream>>>(Ob16, nullptr, nullptr, embeds, ln1g, ln1b, nullptr, x1b);

  // ---- cross-attention + LN2 ----
  gemm_q2kv2<<<dim3(24, 64), blk, 0, stream>>>(x1b, Wq2t, QKV, encb, Wk2t, KV2);
  transpose_v<<<dim3(32, 128), blk, 0, stream>>>(KV2, Vtb, 2048, 1024);
  flash_attn<0><<<dim3(8, 128), blk, 0, stream>>>(QKV, KV2, Vtb, Hd, 3072, 2048);
  gemm_bt<0><<<dim3(8, 64), blk, 0, stream>>>(Hd, Wo2b, Ob16, nullptr, 1024, 1024, 1024, 0);
  ln_res<1, 1><<<8192, blk, 0, stream>>>(Ob16, nullptr, nullptr, x1b, ln2g, ln2b, nullptr, x2b);

  // ---- feed-forward + LN3 ----
  gemm_bt<2><<<dim3(32, 64), blk, 0, stream>>>(x2b, W1b, Hff, b1, 1024, 1024, 4096, 0);
  gemm_bt<0><<<dim3(8, 64, 2), blk, 0, stream>>>(Hff, W2b, Ob16, nullptr, 4096, 2048, 1024, ZC16);
  ln_res<1, 1><<<8192, blk, 0, stream>>>(Ob16, Ob16b, b2, x2b, ln3g, ln3b, out, nullptr);
}